// Round 19
// baseline (253.681 us; speedup 1.0000x reference)
//
#include <hip/hip_runtime.h>

#define EOT_ID 50256

typedef __attribute__((ext_vector_type(8))) short bf16x8;
typedef __attribute__((ext_vector_type(4))) float f32x4;
typedef __attribute__((ext_vector_type(16))) float f32x16;

#define GLOAD_LDS(g, l)                                                        \
  __builtin_amdgcn_global_load_lds(                                            \
      (const __attribute__((address_space(1))) unsigned int*)(g),              \
      (__attribute__((address_space(3))) unsigned int*)(l), 16, 0, 0)

__device__ __forceinline__ unsigned short f2bf(float f) {
  union { float f; unsigned int u; } v; v.f = f;
  unsigned int r = v.u + 0x7FFFu + ((v.u >> 16) & 1u);
  return (unsigned short)(r >> 16);
}
__device__ __forceinline__ float bf2f(unsigned short b) {
  union { unsigned int u; float f; } v; v.u = ((unsigned int)b) << 16;
  return v.f;
}
__device__ __forceinline__ unsigned int cvtpk(float lo, float hi) {
  unsigned int r;
  asm("v_cvt_pk_bf16_f32 %0, %1, %2" : "=v"(r) : "v"(lo), "v"(hi));
  return r;
}
__device__ __forceinline__ void plswap(unsigned int& a, unsigned int& b) {
  asm volatile("v_permlane32_swap_b32 %0, %1" : "+v"(a), "+v"(b));
}
union U8 { unsigned int u[4]; bf16x8 v; };

// ---------------- RoPE tables: cos/sin [2048][32] ----------------
__global__ void rope_tab_kernel(float* __restrict__ ct, float* __restrict__ st) {
  const int idx = blockIdx.x * 256 + threadIdx.x;   // 65536
  const int s = idx >> 5, i = idx & 31;
  const float ang = (float)s * exp2f(-10.0f * (float)i / 31.0f);  // (1/1024)^(i/31)
  float sv, cv;
  sincosf(ang, &sv, &cv);
  ct[idx] = cv;
  st[idx] = sv;
}

// ---------------- doc-start: qstart[i] = latest j<=i with ids[j]==EOT else 0 ----
__global__ __launch_bounds__(1024)
void docs_kernel(const int* __restrict__ ids, int* __restrict__ qstart) {
  __shared__ int a[2048], b2[2048];
  const int t = threadIdx.x;
  for (int i = t; i < 2048; i += 1024)
    a[i] = (ids[i] == EOT_ID) ? i : 0;
  __syncthreads();
  int* cur = a; int* nxt = b2;
  for (int off = 1; off < 2048; off <<= 1) {
    for (int i = t; i < 2048; i += 1024) {
      int v = cur[i];
      if (i >= off) { int u = cur[i - off]; v = (u > v) ? u : v; }
      nxt[i] = v;
    }
    __syncthreads();
    int* tmp = cur; cur = nxt; nxt = tmp;
  }
  for (int i = t; i < 2048; i += 1024) qstart[i] = cur[i];
}

// ---------------- weight transpose f32 [K][N] -> bf16 [N][K] ----------------
__global__ __launch_bounds__(256)
void wtrans_kernel(const float* __restrict__ in, unsigned short* __restrict__ out,
                   int K, int N) {
  __shared__ float tile[32][33];
  const int nb = N >> 5;
  const int k0 = (blockIdx.x / nb) << 5, n0 = (blockIdx.x % nb) << 5;
  const int tx = threadIdx.x & 31, ty = threadIdx.x >> 5;
#pragma unroll
  for (int p = 0; p < 4; p++)
    tile[ty + p * 8][tx] = in[(size_t)(k0 + ty + p * 8) * N + n0 + tx];
  __syncthreads();
#pragma unroll
  for (int p = 0; p < 4; p++)
    out[(size_t)(n0 + ty + p * 8) * K + k0 + tx] = f2bf(tile[tx][ty + p * 8]);
}

// ---------------- K-split reduce: out = bf16(p0+p1+p2+p3) + f32 res ----------------
__global__ __launch_bounds__(256)
void add5_kernel(const unsigned short* __restrict__ p0,
                 const unsigned short* __restrict__ p1,
                 const unsigned short* __restrict__ p2,
                 const unsigned short* __restrict__ p3,
                 const float* __restrict__ res, float* __restrict__ out) {
  const int i = (blockIdx.x * 256 + threadIdx.x) * 4;
  const ushort4 a = *(const ushort4*)(p0 + i);
  const ushort4 b = *(const ushort4*)(p1 + i);
  const ushort4 c = *(const ushort4*)(p2 + i);
  const ushort4 d = *(const ushort4*)(p3 + i);
  float4 e = *(const float4*)(res + i);
  e.x += bf2f(a.x) + bf2f(b.x) + bf2f(c.x) + bf2f(d.x);
  e.y += bf2f(a.y) + bf2f(b.y) + bf2f(c.y) + bf2f(d.y);
  e.z += bf2f(a.z) + bf2f(b.z) + bf2f(c.z) + bf2f(d.z);
  e.w += bf2f(a.w) + bf2f(b.w) + bf2f(c.w) + bf2f(d.w);
  *(float4*)(out + i) = e;
}

// ---------------- LayerNorm (optional residual mix) ----------------
template<bool MIX>
__global__ __launch_bounds__(256)
void ln_kernel(const float* __restrict__ x, const float* __restrict__ x0,
               const float* __restrict__ lam, const float* __restrict__ w,
               float* __restrict__ xm, unsigned short* __restrict__ xn) {
  __shared__ float red[8];
  const int row = blockIdx.x, t = threadIdx.x;
  const size_t base = (size_t)row << 10;
  float4 v = *(const float4*)(x + base + t * 4);
  if (MIX) {
    const float l0 = lam[0], l1 = lam[1];
    const float4 v0 = *(const float4*)(x0 + base + t * 4);
    v.x = l0 * v.x + l1 * v0.x;
    v.y = l0 * v.y + l1 * v0.y;
    v.z = l0 * v.z + l1 * v0.z;
    v.w = l0 * v.w + l1 * v0.w;
    *(float4*)(xm + base + t * 4) = v;
  }
  float s = v.x + v.y + v.z + v.w;
  float q = v.x * v.x + v.y * v.y + v.z * v.z + v.w * v.w;
#pragma unroll
  for (int off = 1; off < 64; off <<= 1) {
    s += __shfl_xor(s, off);
    q += __shfl_xor(q, off);
  }
  const int wid = t >> 6;
  if ((t & 63) == 0) { red[wid] = s; red[4 + wid] = q; }
  __syncthreads();
  s = red[0] + red[1] + red[2] + red[3];
  q = red[4] + red[5] + red[6] + red[7];
  const float mu = s * (1.0f / 1024.0f);
  const float var = q * (1.0f / 1024.0f) - mu * mu;
  const float rstd = rsqrtf(var + 1e-6f);
  const float4 wv = *(const float4*)(w + t * 4);
  ushort4 u;
  u.x = f2bf((v.x - mu) * rstd * wv.x);
  u.y = f2bf((v.y - mu) * rstd * wv.y);
  u.z = f2bf((v.z - mu) * rstd * wv.z);
  u.w = f2bf((v.w - mu) * rstd * wv.w);
  *(ushort4*)(xn + base + t * 4) = u;
}

// ---------------- GEMM (128-tile, 2-phase): used for wo ----------------
template<int EPI, int BM, int BK>
__global__ __launch_bounds__(256, 4)
void gemm_bt(const unsigned short* __restrict__ A,
             const unsigned short* __restrict__ Bt,
             void* __restrict__ Cout,
             const float* __restrict__ res,
             int M, int N, int K) {
  __shared__ unsigned short As[2][BM * BK];
  __shared__ unsigned short Bs[2][128 * BK];
  const int t = threadIdx.x;
  const int wid = t >> 6;
  const int lane = t & 63;
  const int ln = lane & 15, kg = lane >> 4;
  const int nbm = M / BM;
  const int xcd = (int)blockIdx.x & 7, rr = (int)blockIdx.x >> 3;
  const int slab = nbm >> 3;
  const int bm = xcd * slab + (rr % slab);
  const int bn = rr / slab;
  const int m0 = bm * BM, n0 = bn << 7;
  const int wrow = (BM == 128) ? ((wid >> 1) * 64) : 0;
  const int wcol = (BM == 128) ? ((wid & 1) * 64) : (wid * 32);
  constexpr int NJ = (BM == 128) ? 4 : 2;
  constexpr int LA = BM * BK / 2048;
  constexpr int LB = 128 * BK / 2048;
  constexpr int KC = BK / 32;

  f32x4 acc[4][NJ] = {};

  const unsigned short* Abase = A + (size_t)m0 * K;
  const unsigned short* Bbase = Bt + (size_t)n0 * K;

  auto swz = [&](int row, int chunk) -> int {
    if constexpr (BK == 32) return chunk ^ ((row >> 1) & 3);
    else                    return chunk ^ (row & 7);
  };

  auto STAGE = [&](int bb, int kt) {
#pragma unroll
    for (int p = 0; p < LA; p++) {
      const int e = t * 8 + p * 2048;
      const int r = e / BK;
      const int cs = swz(r, (e >> 3) & (BK / 8 - 1));
      GLOAD_LDS(Abase + (size_t)r * K + kt + cs * 8, &As[bb][p * 2048 + wid * 512]);
    }
#pragma unroll
    for (int p = 0; p < LB; p++) {
      const int e = t * 8 + p * 2048;
      const int r = e / BK;
      const int cs = swz(r, (e >> 3) & (BK / 8 - 1));
      GLOAD_LDS(Bbase + (size_t)r * K + kt + cs * 8, &Bs[bb][p * 2048 + wid * 512]);
    }
  };

  STAGE(0, 0);
  int cur = 0;
  const int nk = K / BK;
  for (int ki = 0; ki < nk; ki++) {
    if (ki + 1 < nk) {
      STAGE(cur ^ 1, (ki + 1) * BK);
      if constexpr (LA + LB == 4)
        asm volatile("s_waitcnt vmcnt(4)" ::: "memory");
      else
        asm volatile("s_waitcnt vmcnt(6)" ::: "memory");
    } else {
      asm volatile("s_waitcnt vmcnt(0)" ::: "memory");
    }
    __builtin_amdgcn_s_barrier();

#pragma unroll
    for (int c = 0; c < KC; c++) {
      bf16x8 af[4], bfr[NJ];
#pragma unroll
      for (int i = 0; i < 4; i++) {
        const int ra = wrow + i * 16 + ln;
        af[i] = *(const bf16x8*)(&As[cur][ra * BK + swz(ra, c * 4 + kg) * 8]);
      }
#pragma unroll
      for (int j = 0; j < NJ; j++) {
        const int rb = wcol + j * 16 + ln;
        bfr[j] = *(const bf16x8*)(&Bs[cur][rb * BK + swz(rb, c * 4 + kg) * 8]);
      }
#pragma unroll
      for (int i = 0; i < 4; i++)
#pragma unroll
        for (int j = 0; j < NJ; j++)
          acc[i][j] = __builtin_amdgcn_mfma_f32_16x16x32_bf16(af[i], bfr[j], acc[i][j], 0, 0, 0);
    }

    __builtin_amdgcn_s_barrier();
    cur ^= 1;
  }

#pragma unroll
  for (int i = 0; i < 4; i++) {
#pragma unroll
    for (int j = 0; j < NJ; j++) {
#pragma unroll
      for (int r = 0; r < 4; r++) {
        const int row = m0 + wrow + i * 16 + kg * 4 + r;
        const int col = n0 + wcol + j * 16 + ln;
        const size_t idx = (size_t)row * N + col;
        float v = acc[i][j][r];
        if (EPI == 0) {
          ((float*)Cout)[idx] = v;
        } else if (EPI == 1) {
          ((float*)Cout)[idx] = v + res[idx];
        } else if (EPI == 2) {
          v = fmaxf(v, 0.0f);
          ((unsigned short*)Cout)[idx] = f2bf(v * v);
        } else {
          ((unsigned short*)Cout)[idx] = f2bf(v);
        }
      }
    }
  }
}

// ---------------- GEMM 256x256 8-phase (T2+T3+T4+T5): qkv, fc, proj(K-split) ----
#define SWZ9(x) ((x) ^ ((((x) >> 9) & 1) << 5))

#define RD_A(BUF, QM)                                                          \
  {                                                                            \
    const char* sb_ = smem + (((BUF)*2 + 0) * 2 + (QM)) * 16384;               \
    _Pragma("unroll") for (int i_ = 0; i_ < 4; i_++)                           \
    _Pragma("unroll") for (int kc_ = 0; kc_ < 2; kc_++) {                      \
      int x_ = kc_ * 8192 + (wr * 64 + i_ * 16 + ln) * 64 + kg * 16;           \
      Af[i_][kc_] = *(const bf16x8*)(sb_ + SWZ9(x_));                          \
    }                                                                          \
  }

#define RD_B(BUF, QN, BARR)                                                    \
  {                                                                            \
    const char* sb_ = smem + (((BUF)*2 + 1) * 2 + (QN)) * 16384;               \
    _Pragma("unroll") for (int j_ = 0; j_ < 2; j_++)                           \
    _Pragma("unroll") for (int kc_ = 0; kc_ < 2; kc_++) {                      \
      int x_ = kc_ * 8192 + (wc * 32 + j_ * 16 + ln) * 64 + kg * 16;           \
      BARR[j_][kc_] = *(const bf16x8*)(sb_ + SWZ9(x_));                        \
    }                                                                          \
  }

#define MFMAQ(QM, QN, BARR)                                                    \
  _Pragma("unroll") for (int i_ = 0; i_ < 4; i_++)                             \
  _Pragma("unroll") for (int j_ = 0; j_ < 2; j_++)                             \
  _Pragma("unroll") for (int kc_ = 0; kc_ < 2; kc_++)                          \
    acc[QM][QN][i_][j_] = __builtin_amdgcn_mfma_f32_16x16x32_bf16(             \
        Af[i_][kc_], BARR[j_][kc_], acc[QM][QN][i_][j_], 0, 0, 0);

#define PHTAIL()                                                               \
  __builtin_amdgcn_s_barrier();                                                \
  asm volatile("s_waitcnt lgkmcnt(0)" ::: "memory");                           \
  __builtin_amdgcn_sched_barrier(0);                                           \
  __builtin_amdgcn_s_setprio(1)

#define PHEND()                                                                \
  __builtin_amdgcn_s_setprio(0);                                               \
  __builtin_amdgcn_s_barrier()

template<int EPI, bool KSPLIT4>
__global__ __launch_bounds__(512, 2)
void gemm256(const unsigned short* __restrict__ A,
             const unsigned short* __restrict__ Bt,
             void* __restrict__ Cout,
             int M, int N, int Kfull, int Klen, int nInner,
             unsigned short* __restrict__ o1, unsigned short* __restrict__ o2,
             unsigned short* __restrict__ o3) {
  extern __shared__ char smem[];
  const int tid = threadIdx.x;
  const int wid = tid >> 6, lane = tid & 63;
  const int wr = wid >> 2, wc = wid & 3;
  const int ln = lane & 15, kg = lane >> 4;
  int blkid = (int)blockIdx.x;
  int split = 0;
  if constexpr (KSPLIT4) {
    split = blkid / nInner;
    blkid -= split * nInner;
  }
  const int nbm = M >> 8;
  const int xcd = blkid & 7, rr = blkid >> 3;
  const int slab = nbm >> 3;
  const int bm = xcd * slab + (rr % slab);
  const int bn = rr / slab;
  const int m0 = bm << 8, n0 = bn << 8;
  const size_t K2 = (size_t)Kfull * 2;
  const size_t kb0 = (size_t)split * Klen * 2;
  const char* Ac = (const char*)A;
  const char* Bc = (const char*)Bt;

  f32x4 acc[2][2][4][2] = {};
  bf16x8 Af[4][2], B0[2][2], B1[2][2];

  auto STG = [&](int buf, int ab, int h, int tile) {
    const char* gb = ab ? Bc : Ac;
    const int ro = (ab ? n0 : m0) + h * 128;
    char* db = smem + ((buf * 2 + ab) * 2 + h) * 16384;
#pragma unroll
    for (int q = 0; q < 2; q++) {
      const int p0 = q * 8192 + tid * 16;
      const int lin = SWZ9(p0);
      GLOAD_LDS(gb + (size_t)(ro + ((lin >> 6) & 127)) * K2 + kb0 +
                    (size_t)tile * 128 + (lin >> 13) * 64 + (lin & 63),
                db + p0);
    }
  };

  STG(0, 0, 0, 0); STG(0, 0, 1, 0); STG(0, 1, 0, 0); STG(0, 1, 1, 0);
  STG(1, 0, 0, 1); STG(1, 1, 0, 1); STG(1, 1, 1, 1);
  asm volatile("s_waitcnt vmcnt(6)" ::: "memory");
  __builtin_amdgcn_s_barrier();

  const int niter = Klen >> 7;   // pairs of 64-wide K-tiles
  for (int it = 0; it < niter; it++) {
    const int tA = 2 * it, tB = tA + 1;
    const bool more = (it + 1 < niter);

    RD_A(0, 0); RD_B(0, 0, B0);
    STG(1, 0, 1, tB);
    PHTAIL(); MFMAQ(0, 0, B0); PHEND();
    RD_B(0, 1, B1);
    if (more) STG(0, 0, 0, tA + 2);
    PHTAIL(); MFMAQ(0, 1, B1); PHEND();
    RD_A(0, 1);
    if (more) STG(0, 1, 0, tA + 2);
    PHTAIL(); MFMAQ(1, 0, B0); PHEND();
    if (more) {
      STG(0, 1, 1, tA + 2);
      asm volatile("s_waitcnt vmcnt(6)" ::: "memory");
    } else {
      asm volatile("s_waitcnt vmcnt(0)" ::: "memory");
    }
    PHTAIL(); MFMAQ(1, 1, B1); PHEND();
    RD_A(1, 0); RD_B(1, 0, B0);
    if (more) STG(0, 0, 1, tA + 2);
    PHTAIL(); MFMAQ(0, 0, B0); PHEND();
    RD_B(1, 1, B1);
    if (more) STG(1, 0, 0, tB + 2);
    PHTAIL(); MFMAQ(0, 1, B1); PHEND();
    RD_A(1, 1);
    if (more) STG(1, 1, 0, tB + 2);
    PHTAIL(); MFMAQ(1, 0, B0); PHEND();
    if (more) {
      STG(1, 1, 1, tB + 2);
      asm volatile("s_waitcnt vmcnt(6)" ::: "memory");
    }
    PHTAIL(); MFMAQ(1, 1, B1); PHEND();
  }

  unsigned short* bout = (unsigned short*)Cout;
  if constexpr (KSPLIT4) {
    if (split == 1) bout = o1;
    else if (split == 2) bout = o2;
    else if (split == 3) bout = o3;
  }

#pragma unroll
  for (int qm = 0; qm < 2; qm++)
#pragma unroll
    for (int qn = 0; qn < 2; qn++)
#pragma unroll
      for (int i = 0; i < 4; i++)
#pragma unroll
        for (int j = 0; j < 2; j++)
#pragma unroll
          for (int r = 0; r < 4; r++) {
            const int row = m0 + qm * 128 + wr * 64 + i * 16 + kg * 4 + r;
            const int col = n0 + qn * 128 + wc * 32 + j * 16 + ln;
            const size_t idx = (size_t)row * N + col;
            float v = acc[qm][qn][i][j][r];
            if (EPI == 2) {
              v = fmaxf(v, 0.0f);
              ((unsigned short*)Cout)[idx] = f2bf(v * v);
            } else if (EPI == 3) {
              ((unsigned short*)Cout)[idx] = f2bf(v);
            } else {
              bout[idx] = f2bf(v);      // bf16 K-split partial
            }
          }
}

// ---------------- RoPE + RMSNorm + v-mix (qkv in bf16) ----------------
__global__ __launch_bounds__(256)
void rope_rms_kernel(const unsigned short* __restrict__ qkv,
                     const float* __restrict__ ct, const float* __restrict__ st,
                     const float* __restrict__ ve, const float* __restrict__ salam,
                     unsigned short* __restrict__ Qh, unsigned short* __restrict__ Kh,
                     unsigned short* __restrict__ Vt) {
  const int t = threadIdx.x;
  const int wid = t >> 6, i = t & 63;
  const int g = blockIdx.x * 4 + wid;      // (b,s,h)
  const int b = g >> 14;
  const int s = (g >> 3) & 2047;
  const int h = g & 7;
  const unsigned short* base = qkv + (size_t)(b * 2048 + s) * 3072 + h * 128;
  float c = 1.0f, sn = 0.0f;
  if (i < 32) { c = ct[s * 32 + i]; sn = st[s * 32 + i]; }
  const float q1 = bf2f(base[i]), q2 = bf2f(base[64 + i]);
  const float k1 = bf2f(base[1024 + i]), k2 = bf2f(base[1024 + 64 + i]);
  const float q1r = q1 * c + q2 * sn, q2r = q2 * c - q1 * sn;
  const float k1r = k1 * c + k2 * sn, k2r = k2 * c - k1 * sn;
  float sq = q1r * q1r + q2r * q2r;
  float sk = k1r * k1r + k2r * k2r;
#pragma unroll
  for (int off = 1; off < 64; off <<= 1) {
    sq += __shfl_xor(sq, off);
    sk += __shfl_xor(sk, off);
  }
  const float eps = 1.1920929e-7f;
  const float rq = rsqrtf(sq * (1.0f / 128.0f) + eps);
  const float rk = rsqrtf(sk * (1.0f / 128.0f) + eps);
  unsigned short* qp = Qh + (((size_t)(b * 2048 + s) * 8 + h) << 7);
  unsigned short* kp = Kh + (((size_t)(b * 2048 + s) * 8 + h) << 7);
  qp[i] = f2bf(q1r * rq); qp[64 + i] = f2bf(q2r * rq);
  kp[i] = f2bf(k1r * rk); kp[64 + i] = f2bf(k2r * rk);
  const float l0 = salam[0], l1 = salam[1];
  const float* vep = ve + (size_t)s * 1024 + h * 128;
  const float v1 = l0 * bf2f(base[2048 + i]) + l1 * vep[i];
  const float v2 = l0 * bf2f(base[2048 + 64 + i]) + l1 * vep[64 + i];
  unsigned short* vp = Vt + (((size_t)(b * 8 + h) * 128) << 11) + s;
  vp[(size_t)i << 11] = f2bf(v1);
  vp[(size_t)(64 + i) << 11] = f2bf(v2);
}

// ---------------- flash attention, doc-causal (barrier-free waves) ----------------
// 512 blocks x 4 waves, 64KB LDS -> 2 independent blocks/CU (8 waves).
// Block = (pid, qhalf, bh): phase 0 = half qhalf of qt=pid; phase 1 = half
// qhalf^1 of qt=31-pid -> exactly 65 KV-tiles per block (perfect balance).
// Inside a phase: wave wid takes tiles wid, wid+4, ... with a PRIVATE 16KB
// K/V LDS quarter -- no block barriers, vmcnt(0) is the only sync (r17 core).
// Phase ends with the r16-style 4-way (m,l,o) merge through idle LDS.
__global__ __launch_bounds__(256, 2)
void attn_kernel(const unsigned short* __restrict__ Qh,
                 const unsigned short* __restrict__ Kh,
                 const unsigned short* __restrict__ Vt,
                 const int* __restrict__ qstart,
                 unsigned short* __restrict__ Out) {
  extern __shared__ char asmem[];   // 64KB: [4 waves][K 8KB | V 8KB]

  const int blk = blockIdx.x;        // 512 blocks
  const int pid = blk >> 5;          // 0..15
  const int qhalf = (blk >> 4) & 1;
  const int bh = blk & 15;
  const int b = bh >> 3, h = bh & 7;
  const int t = threadIdx.x;
  const int wid = t >> 6, lane = t & 63;
  const int ln5 = lane & 31, hi = lane >> 5;
  const float SC = 0.12f * 1.4426950408889634f;

  char* Kb = asmem + wid * 16384;
  char* Vb = Kb + 8192;

  auto STAGE = [&](int kt) {
#pragma unroll
    for (int r = 0; r < 8; r++) {
      const int e = lane * 16 + r * 1024;       // byte in 8KB K tile
      const int row = e >> 8;                   // key 0..31 (256B rows)
      const int ch = (e >> 4) & 15;
      const int sch = ch ^ ((row ^ (row >> 3)) & 7);
      GLOAD_LDS(Kh + (((size_t)(b * 2048 + kt + row) * 8 + h) << 7) + sch * 8,
                Kb + r * 1024 + (lane << 4));
    }
#pragma unroll
    for (int r = 0; r < 8; r++) {
      const int e = lane * 16 + r * 1024;       // byte in 8KB V tile
      const int row = e >> 6;                   // d 0..127 (64B rows)
      const int ch = (e >> 4) & 3;
      const int sch = ch ^ ((row >> 1) & 3);
      GLOAD_LDS(Vt + (((size_t)((b * 8 + h) * 128 + row)) << 11) + kt + sch * 8,
                Vb + r * 1024 + (lane << 4));
    }
  };

  for (int ph = 0; ph < 2; ph++) {
    const int qt = ph ? (31 - pid) : pid;
    const int qh2 = ph ? (qhalf ^ 1) : qhalf;
    const int q0 = qt << 6;
    const int qrow = q0 + qh2 * 32;

    // Q fragments: B-operand (col=q=ln5, k = 16*c + 8*hi + j)
    bf16x8 qf[8];
    {
      const unsigned short* qp =
          Qh + (((size_t)(b * 2048 + qrow + ln5) * 8 + h) << 7) + hi * 8;
#pragma unroll
      for (int c = 0; c < 8; c++) qf[c] = *(const bf16x8*)(qp + c * 16);
    }
    const int qid = qrow + ln5;
    const int qs = qstart[qid];
    int qsmax = qs;
#pragma unroll
    for (int off = 1; off < 32; off <<= 1)
      qsmax = max(qsmax, __shfl_xor(qsmax, off));

    float m = -64.0f, l = 0.0f;
    f32x16 o[4] = {};

    const int kt0 = qstart[qrow] & ~31;        // qstart monotone -> min over rows
    const int T = (qrow + 32 - kt0) >> 5;      // tiles for THIS 32-q half

    __syncthreads();   // previous phase's merge readers done; LDS reusable

    for (int tid2 = wid; tid2 < T; tid2 += 4) {
      const int kt = kt0 + tid2 * 32;
      STAGE(kt);
      asm volatile("s_waitcnt vmcnt(0)" ::: "memory");

      const unsigned short* ksb = (const unsigned short*)Kb;
      const unsigned short* vsb = (const unsigned short*)Vb;

      f32x16 sacc = {};
      {
        const int key = ln5;
        const int kx = (key ^ (key >> 3)) & 7;
        const unsigned short* krow = &ksb[key * 128];
#pragma unroll
        for (int c = 0; c < 8; c++) {
          bf16x8 kf = *(const bf16x8*)(krow + (((2 * c + hi) ^ kx) << 3));
          sacc = __builtin_amdgcn_mfma_f32_32x32x16_bf16(kf, qf[c], sacc, 0, 0, 0);
        }
      }

      const bool full = (kt + 32 <= qrow) && (kt >= qsmax);

      float p[16];
      float mx = -1e30f;
      if (full) {
#pragma unroll
        for (int i2 = 0; i2 < 16; i2++) {
          const float ts = sacc[i2] * SC;
          p[i2] = ts;
          mx = fmaxf(mx, ts);
        }
      } else {
#pragma unroll
        for (int i2 = 0; i2 < 16; i2++) {
          const int key = kt + (i2 & 3) + 8 * (i2 >> 2) + 4 * hi;
          const bool valid = (key <= qid) && (key >= qs);
          const float ts = valid ? sacc[i2] * SC : -1e30f;
          p[i2] = ts;
          mx = fmaxf(mx, ts);
        }
      }
      mx = fmaxf(mx, __shfl_xor(mx, 32));

      const bool dresc = __any(mx - m > 8.0f);
      if (dresc) {
        const float mn = fmaxf(m, mx);
        const float fac = exp2f(m - mn);
        m = mn;
        l *= fac;
#pragma unroll
        for (int r = 0; r < 16; r++) {
          const float fr = __shfl(fac, (r & 3) + 8 * (r >> 2) + 4 * hi);
          o[0][r] *= fr; o[1][r] *= fr; o[2][r] *= fr; o[3][r] *= fr;
        }
      }

      float sum = 0.0f;
#pragma unroll
      for (int i2 = 0; i2 < 16; i2++) {
        const float pv = exp2f(p[i2] - m);     // masked underflows to 0
        p[i2] = pv;
        sum += pv;
      }
      sum += __shfl_xor(sum, 32);
      l += sum;

      bf16x8 pa[2];
#pragma unroll
      for (int bb2 = 0; bb2 < 2; bb2++) {
        unsigned int a0 = cvtpk(p[bb2 * 8 + 0], p[bb2 * 8 + 1]);
        unsigned int b0 = cvtpk(p[bb2 * 8 + 4], p[bb2 * 8 + 5]);
        unsigned int a1 = cvtpk(p[bb2 * 8 + 2], p[bb2 * 8 + 3]);
        unsigned int b1 = cvtpk(p[bb2 * 8 + 6], p[bb2 * 8 + 7]);
        plswap(a0, b0);
        plswap(a1, b1);
        U8 u; u.u[0] = a0; u.u[1] = a1; u.u[2] = b0; u.u[3] = b1;
        pa[bb2] = u.v;
      }

#pragma unroll
      for (int dt = 0; dt < 4; dt++) {
        const int d = dt * 32 + ln5;
        const int dx = (d >> 1) & 3;
        const unsigned short* vrow = &vsb[d * 32];
#pragma unroll
        for (int ks = 0; ks < 2; ks++) {
          bf16x8 vf = *(const bf16x8*)(vrow + (((2 * ks + hi) ^ dx) << 3));
          o[dt] = __builtin_amdgcn_mfma_f32_32x32x16_bf16(pa[ks], vf, o[dt], 0, 0, 0);
        }
      }
    }

    // ---- 4-way merge through (now idle) LDS ----
    __syncthreads();
    float* oex = (float*)asmem;                 // [3][64 lanes][65] = 49,920 B
    float* mlx = (float*)(asmem + 49920);       // [3][32][2]
    if (wid != 0) {
      if (lane < 32) {
        mlx[((wid - 1) * 32 + lane) * 2 + 0] = m;
        mlx[((wid - 1) * 32 + lane) * 2 + 1] = l;
      }
      float* dst = oex + ((wid - 1) * 64 + lane) * 65;
#pragma unroll
      for (int dt = 0; dt < 4; dt++)
#pragma unroll
        for (int r = 0; r < 16; r++) dst[dt * 16 + r] = o[dt][r];
    }
    __syncthreads();
    if (wid == 0) {
      float mm[3], ll[3];
#pragma unroll
      for (int j = 0; j < 3; j++) {
        mm[j] = mlx[(j * 32 + ln5) * 2 + 0];
        ll[j] = mlx[(j * 32 + ln5) * 2 + 1];
      }
      const float ms = fmaxf(fmaxf(m, mm[0]), fmaxf(mm[1], mm[2]));
      const float a0 = exp2f(m - ms);
      const float a1 = exp2f(mm[0] - ms);
      const float a2 = exp2f(mm[1] - ms);
      const float a3 = exp2f(mm[2] - ms);
      const float inv = 1.0f / (l * a0 + ll[0] * a1 + ll[1] * a2 + ll[2] * a3);
      const float* s1 = oex + (0 * 64 + lane) * 65;
      const float* s2 = oex + (1 * 64 + lane) * 65;
      const float* s3 = oex + (2 * 64 + lane) * 65;
#pragma unroll
      for (int r = 0; r < 16; r++) {
        const int crow = (r & 3) + 8 * (r >> 2) + 4 * hi;
        const float a0r = __shfl(a0, crow);
        const float a1r = __shfl(a1, crow);
        const float a2r = __shfl(a2, crow);
        const float a3r = __shfl(a3, crow);
        const float ivr = __shfl(inv, crow);
        const int q = qrow + crow;
        unsigned short* op = Out + (((size_t)(b * 2048 + q)) << 10) + h * 128 + ln5;
#pragma unroll
        for (int dt = 0; dt < 4; dt++)
          op[dt * 32] = f2bf((o[dt][r] * a0r + s1[dt * 16 + r] * a1r +
                              s2[dt * 16 + r] * a2r + s3[dt * 16 + r] * a3r) * ivr);
      }
    }
  }
}

// ---------------- launcher ----------------
extern "C" void kernel_launch(void* const* d_in, const int* in_sizes, int n_in,
                              void* d_out, int out_size, void* d_ws, size_t ws_size,
                              hipStream_t stream) {
  const float* x     = (const float*)d_in[0];
  const float* vemb  = (const float*)d_in[1];
  const float* x0    = (const float*)d_in[2];
  const float* lam   = (const float*)d_in[3];
  const float* slam  = (const float*)d_in[4];
  const float* ln1w  = (const float*)d_in[5];
  const float* ln2w  = (const float*)d_in[6];
  const float* wqkv  = (const float*)d_in[7];
  const float* wo    = (const float*)d_in[8];
  const float* wfc   = (const float*)d_in[9];
  const float* wproj = (const float*)d_in[10];
  const int*   ids   = (const int*)d_in[11];

  char* ws = (char*)d_ws;
  unsigned short* wqkvT  = (unsigned short*)(ws + 0);          //  6 MB
  unsigned short* woT    = (unsigned short*)(ws + 6291456);    //  2 MB
  unsigned short* wfcT   = (unsigned short*)(ws + 8388608);    //  8 MB
  unsigned short* wprojT = (unsigned short*)(ws + 16777216);   //  8 MB
  float*          xm     = (float*)(ws + 25165824);            // 16 MB
  unsigned short* qkv    = (unsigned short*)(ws + 41943040);   // 24 MB (bf16)
  unsigned short* hbuf   = (unsigned short*)(ws + 41943040);   // reuse (32 MB)
  unsigned short* xn1    = (unsigned short*)(ws + 92274688);   //  8 MB
  unsigned short* ao     = (unsigned short*)(ws + 92274688);   // reuse
  unsigned short* qh     = (unsigned short*)(ws + 100663296);  //  8 MB
  unsigned short* xn2    = (unsigned short*)(ws + 100663296);  // reuse
  unsigned short* kh     = (unsigned short*)(ws + 109051904);  //  8 MB
  unsigned short* vt     = (unsigned short*)(ws + 117440512);  //  8 MB
  float*          x2     = (float*)(ws + 109051904);           // reuse kh+vt (16 MB)
  float*          ctab   = (float*)(ws + 125829120);
  float*          stab   = (float*)(ws + 126091264);
  int*            qstart = (int*)(ws + 126353408);
  // bf16 K-split partials (8 MB each, all regions dead at proj time):
  unsigned short* P0 = (unsigned short*)(ws + 0);          // wqkvT+woT
  unsigned short* P1 = (unsigned short*)(ws + 8388608);    // wfcT (dead after fc)
  unsigned short* P2 = (unsigned short*)(ws + 25165824);   // xm lower half (dead after wo)
  unsigned short* P3 = (unsigned short*)(ws + 33554432);   // xm upper half

  static int attr_done = 0;
  if (!attr_done) {
    hipFuncSetAttribute((const void*)gemm256<3, false>,
                        hipFuncAttributeMaxDynamicSharedMemorySize, 131072);
    hipFuncSetAttribute((const void*)gemm256<2, false>,
                        hipFuncAttributeMaxDynamicSharedMemorySize, 131072);
    hipFuncSetAttribute((const void*)gemm256<4, true>,
                        hipFuncAttributeMaxDynamicSharedMemorySize, 131072);
    hipFuncSetAttribute((const void*)attn_kernel,
                        hipFuncAttributeMaxDynamicSharedMemorySize, 65536);
    attr_done = 1;
  }

  rope_tab_kernel<<<dim3(256), dim3(256), 0, stream>>>(ctab, stab);
  docs_kernel<<<dim3(1), dim3(1024), 0, stream>>>(ids, qstart);
  wtrans_kernel<<<dim3(32 * 96), dim3(256), 0, stream>>>(wqkv, wqkvT, 1024, 3072);
  wtrans_kernel<<<dim3(32 * 32), dim3(256), 0, stream>>>(wo, woT, 1024, 1024);
  wtrans_kernel<<<dim3(32 * 128), dim3(256), 0, stream>>>(wfc, wfcT, 1024, 4096);
  wtrans_kernel<<<dim3(128 * 32), dim3(256), 0, stream>>>(wproj, wprojT, 4096, 1024);

  ln_kernel<true><<<dim3(4096), dim3(256), 0, stream>>>(x, x0, lam, ln1w, xm, xn1);
  gemm256<3, false><<<dim3(192), dim3(512), 131072, stream>>>(
      xn1, wqkvT, (void*)qkv, 4096, 3072, 1024, 1024, 0, nullptr, nullptr, nullptr);
  rope_rms_kernel<<<dim3(8192), dim3(256), 0, stream>>>(qkv, ctab, stab, vemb, slam, qh, kh, vt);
  attn_kernel<<<dim3(512), dim3(256), 65536, stream>>>(qh, kh, vt, qstart, ao);
  gemm_bt<1, 64, 64><<<dim3(64 * 8), dim3(256), 0, stream>>>(ao, woT, (void*)x2, xm,
                                                             4096, 1024, 1024);
  ln_kernel<false><<<dim3(4096), dim3(256), 0, stream>>>(x2, (const float*)nullptr,
                                                         (const float*)nullptr, ln2w,
                                                         (float*)nullptr, xn2);
  gemm256<2, false><<<dim3(256), dim3(512), 131072, stream>>>(
      xn2, wfcT, (void*)hbuf, 4096, 4096, 1024, 1024, 0, nullptr, nullptr, nullptr);
  // w_proj via 8-phase template, K-split x4 with bf16 partials (shape == fc)
  gemm256<4, true><<<dim3(256), dim3(512), 131072, stream>>>(
      hbuf, wprojT, (void*)P0, 4096, 1024, 4096, 1024, 64, P1, P2, P3);
  add5_kernel<<<dim3(4096), dim3(256), 0, stream>>>(P0, P1, P2, P3, x2, (float*)d_out);
}

// Round 20
// 240.759 us; speedup vs baseline: 1.0537x; 1.0537x over previous
//
#include <hip/hip_runtime.h>

#define EOT_ID 50256

typedef __attribute__((ext_vector_type(8))) short bf16x8;
typedef __attribute__((ext_vector_type(4))) float f32x4;
typedef __attribute__((ext_vector_type(16))) float f32x16;

#define GLOAD_LDS(g, l)                                                        \
  __builtin_amdgcn_global_load_lds(                                            \
      (const __attribute__((address_space(1))) unsigned int*)(g),              \
      (__attribute__((address_space(3))) unsigned int*)(l), 16, 0, 0)

__device__ __forceinline__ unsigned short f2bf(float f) {
  union { float f; unsigned int u; } v; v.f = f;
  unsigned int r = v.u + 0x7FFFu + ((v.u >> 16) & 1u);
  return (unsigned short)(r >> 16);
}
__device__ __forceinline__ float bf2f(unsigned short b) {
  union { unsigned int u; float f; } v; v.u = ((unsigned int)b) << 16;
  return v.f;
}
__device__ __forceinline__ unsigned int cvtpk(float lo, float hi) {
  unsigned int r;
  asm("v_cvt_pk_bf16_f32 %0, %1, %2" : "=v"(r) : "v"(lo), "v"(hi));
  return r;
}
__device__ __forceinline__ void plswap(unsigned int& a, unsigned int& b) {
  asm volatile("v_permlane32_swap_b32 %0, %1" : "+v"(a), "+v"(b));
}
union U8 { unsigned int u[4]; bf16x8 v; };

// ---------------- prep: RoPE tables (blocks 0..255) + doc-scan (block 256) ----
__global__ __launch_bounds__(256)
void prep_kernel(float* __restrict__ ct, float* __restrict__ st,
                 const int* __restrict__ ids, int* __restrict__ qstart) {
  if (blockIdx.x < 256) {
    const int idx = blockIdx.x * 256 + threadIdx.x;   // 65536
    const int s = idx >> 5, i = idx & 31;
    const float ang = (float)s * exp2f(-10.0f * (float)i / 31.0f);
    float sv, cv;
    sincosf(ang, &sv, &cv);
    ct[idx] = cv;
    st[idx] = sv;
  } else {
    __shared__ int a[2048], b2[2048];
    const int t = threadIdx.x;
    for (int i = t; i < 2048; i += 256)
      a[i] = (ids[i] == EOT_ID) ? i : 0;
    __syncthreads();
    int* cur = a; int* nxt = b2;
    for (int off = 1; off < 2048; off <<= 1) {
      for (int i = t; i < 2048; i += 256) {
        int v = cur[i];
        if (i >= off) { int u = cur[i - off]; v = (u > v) ? u : v; }
        nxt[i] = v;
      }
      __syncthreads();
      int* tmp = cur; cur = nxt; nxt = tmp;
    }
    for (int i = t; i < 2048; i += 256) qstart[i] = cur[i];
  }
}

// ---------------- merged weight transpose f32 [K][N] -> bf16 [N][K] ----------------
// blocks: [0,3072) wqkv (1024x3072); [3072,4096) wo (1024x1024);
// [4096,8192) wfc (1024x4096); [8192,12288) wproj (4096x1024).
__global__ __launch_bounds__(256)
void wtrans4_kernel(const float* __restrict__ wqkv, const float* __restrict__ wo,
                    const float* __restrict__ wfc, const float* __restrict__ wproj,
                    unsigned short* __restrict__ wqkvT, unsigned short* __restrict__ woT,
                    unsigned short* __restrict__ wfcT, unsigned short* __restrict__ wprojT) {
  int blk = blockIdx.x;
  const float* in;
  unsigned short* out;
  int K, N;
  if (blk < 3072)      { in = wqkv;  out = wqkvT;  K = 1024; N = 3072; }
  else if (blk < 4096) { blk -= 3072; in = wo;    out = woT;    K = 1024; N = 1024; }
  else if (blk < 8192) { blk -= 4096; in = wfc;   out = wfcT;   K = 1024; N = 4096; }
  else                 { blk -= 8192; in = wproj; out = wprojT; K = 4096; N = 1024; }
  __shared__ float tile[32][33];
  const int nb = N >> 5;
  const int k0 = (blk / nb) << 5, n0 = (blk % nb) << 5;
  const int tx = threadIdx.x & 31, ty = threadIdx.x >> 5;
#pragma unroll
  for (int p = 0; p < 4; p++)
    tile[ty + p * 8][tx] = in[(size_t)(k0 + ty + p * 8) * N + n0 + tx];
  __syncthreads();
#pragma unroll
  for (int p = 0; p < 4; p++)
    out[(size_t)(n0 + ty + p * 8) * K + k0 + tx] = f2bf(tile[tx][ty + p * 8]);
}

// ---------------- K-split reduce: out = bf16(p0+p1+p2+p3) + f32 res ----------------
__global__ __launch_bounds__(256)
void add5_kernel(const unsigned short* __restrict__ p0,
                 const unsigned short* __restrict__ p1,
                 const unsigned short* __restrict__ p2,
                 const unsigned short* __restrict__ p3,
                 const float* __restrict__ res, float* __restrict__ out) {
  const int i = (blockIdx.x * 256 + threadIdx.x) * 4;
  const ushort4 a = *(const ushort4*)(p0 + i);
  const ushort4 b = *(const ushort4*)(p1 + i);
  const ushort4 c = *(const ushort4*)(p2 + i);
  const ushort4 d = *(const ushort4*)(p3 + i);
  float4 e = *(const float4*)(res + i);
  e.x += bf2f(a.x) + bf2f(b.x) + bf2f(c.x) + bf2f(d.x);
  e.y += bf2f(a.y) + bf2f(b.y) + bf2f(c.y) + bf2f(d.y);
  e.z += bf2f(a.z) + bf2f(b.z) + bf2f(c.z) + bf2f(d.z);
  e.w += bf2f(a.w) + bf2f(b.w) + bf2f(c.w) + bf2f(d.w);
  *(float4*)(out + i) = e;
}

// ---------------- LayerNorm (optional residual mix) ----------------
template<bool MIX>
__global__ __launch_bounds__(256)
void ln_kernel(const float* __restrict__ x, const float* __restrict__ x0,
               const float* __restrict__ lam, const float* __restrict__ w,
               float* __restrict__ xm, unsigned short* __restrict__ xn) {
  __shared__ float red[8];
  const int row = blockIdx.x, t = threadIdx.x;
  const size_t base = (size_t)row << 10;
  float4 v = *(const float4*)(x + base + t * 4);
  if (MIX) {
    const float l0 = lam[0], l1 = lam[1];
    const float4 v0 = *(const float4*)(x0 + base + t * 4);
    v.x = l0 * v.x + l1 * v0.x;
    v.y = l0 * v.y + l1 * v0.y;
    v.z = l0 * v.z + l1 * v0.z;
    v.w = l0 * v.w + l1 * v0.w;
    *(float4*)(xm + base + t * 4) = v;
  }
  float s = v.x + v.y + v.z + v.w;
  float q = v.x * v.x + v.y * v.y + v.z * v.z + v.w * v.w;
#pragma unroll
  for (int off = 1; off < 64; off <<= 1) {
    s += __shfl_xor(s, off);
    q += __shfl_xor(q, off);
  }
  const int wid = t >> 6;
  if ((t & 63) == 0) { red[wid] = s; red[4 + wid] = q; }
  __syncthreads();
  s = red[0] + red[1] + red[2] + red[3];
  q = red[4] + red[5] + red[6] + red[7];
  const float mu = s * (1.0f / 1024.0f);
  const float var = q * (1.0f / 1024.0f) - mu * mu;
  const float rstd = rsqrtf(var + 1e-6f);
  const float4 wv = *(const float4*)(w + t * 4);
  ushort4 u;
  u.x = f2bf((v.x - mu) * rstd * wv.x);
  u.y = f2bf((v.y - mu) * rstd * wv.y);
  u.z = f2bf((v.z - mu) * rstd * wv.z);
  u.w = f2bf((v.w - mu) * rstd * wv.w);
  *(ushort4*)(xn + base + t * 4) = u;
}

// ---------------- GEMM (128-tile, 2-phase): used for wo ----------------
template<int EPI, int BM, int BK>
__global__ __launch_bounds__(256, 4)
void gemm_bt(const unsigned short* __restrict__ A,
             const unsigned short* __restrict__ Bt,
             void* __restrict__ Cout,
             const float* __restrict__ res,
             int M, int N, int K) {
  __shared__ unsigned short As[2][BM * BK];
  __shared__ unsigned short Bs[2][128 * BK];
  const int t = threadIdx.x;
  const int wid = t >> 6;
  const int lane = t & 63;
  const int ln = lane & 15, kg = lane >> 4;
  const int nbm = M / BM;
  const int xcd = (int)blockIdx.x & 7, rr = (int)blockIdx.x >> 3;
  const int slab = nbm >> 3;
  const int bm = xcd * slab + (rr % slab);
  const int bn = rr / slab;
  const int m0 = bm * BM, n0 = bn << 7;
  const int wrow = (BM == 128) ? ((wid >> 1) * 64) : 0;
  const int wcol = (BM == 128) ? ((wid & 1) * 64) : (wid * 32);
  constexpr int NJ = (BM == 128) ? 4 : 2;
  constexpr int LA = BM * BK / 2048;
  constexpr int LB = 128 * BK / 2048;
  constexpr int KC = BK / 32;

  f32x4 acc[4][NJ] = {};

  const unsigned short* Abase = A + (size_t)m0 * K;
  const unsigned short* Bbase = Bt + (size_t)n0 * K;

  auto swz = [&](int row, int chunk) -> int {
    if constexpr (BK == 32) return chunk ^ ((row >> 1) & 3);
    else                    return chunk ^ (row & 7);
  };

  auto STAGE = [&](int bb, int kt) {
#pragma unroll
    for (int p = 0; p < LA; p++) {
      const int e = t * 8 + p * 2048;
      const int r = e / BK;
      const int cs = swz(r, (e >> 3) & (BK / 8 - 1));
      GLOAD_LDS(Abase + (size_t)r * K + kt + cs * 8, &As[bb][p * 2048 + wid * 512]);
    }
#pragma unroll
    for (int p = 0; p < LB; p++) {
      const int e = t * 8 + p * 2048;
      const int r = e / BK;
      const int cs = swz(r, (e >> 3) & (BK / 8 - 1));
      GLOAD_LDS(Bbase + (size_t)r * K + kt + cs * 8, &Bs[bb][p * 2048 + wid * 512]);
    }
  };

  STAGE(0, 0);
  int cur = 0;
  const int nk = K / BK;
  for (int ki = 0; ki < nk; ki++) {
    if (ki + 1 < nk) {
      STAGE(cur ^ 1, (ki + 1) * BK);
      if constexpr (LA + LB == 4)
        asm volatile("s_waitcnt vmcnt(4)" ::: "memory");
      else
        asm volatile("s_waitcnt vmcnt(6)" ::: "memory");
    } else {
      asm volatile("s_waitcnt vmcnt(0)" ::: "memory");
    }
    __builtin_amdgcn_s_barrier();

#pragma unroll
    for (int c = 0; c < KC; c++) {
      bf16x8 af[4], bfr[NJ];
#pragma unroll
      for (int i = 0; i < 4; i++) {
        const int ra = wrow + i * 16 + ln;
        af[i] = *(const bf16x8*)(&As[cur][ra * BK + swz(ra, c * 4 + kg) * 8]);
      }
#pragma unroll
      for (int j = 0; j < NJ; j++) {
        const int rb = wcol + j * 16 + ln;
        bfr[j] = *(const bf16x8*)(&Bs[cur][rb * BK + swz(rb, c * 4 + kg) * 8]);
      }
#pragma unroll
      for (int i = 0; i < 4; i++)
#pragma unroll
        for (int j = 0; j < NJ; j++)
          acc[i][j] = __builtin_amdgcn_mfma_f32_16x16x32_bf16(af[i], bfr[j], acc[i][j], 0, 0, 0);
    }

    __builtin_amdgcn_s_barrier();
    cur ^= 1;
  }

#pragma unroll
  for (int i = 0; i < 4; i++) {
#pragma unroll
    for (int j = 0; j < NJ; j++) {
#pragma unroll
      for (int r = 0; r < 4; r++) {
        const int row = m0 + wrow + i * 16 + kg * 4 + r;
        const int col = n0 + wcol + j * 16 + ln;
        const size_t idx = (size_t)row * N + col;
        float v = acc[i][j][r];
        if (EPI == 0) {
          ((float*)Cout)[idx] = v;
        } else if (EPI == 1) {
          ((float*)Cout)[idx] = v + res[idx];
        } else if (EPI == 2) {
          v = fmaxf(v, 0.0f);
          ((unsigned short*)Cout)[idx] = f2bf(v * v);
        } else {
          ((unsigned short*)Cout)[idx] = f2bf(v);
        }
      }
    }
  }
}

// ---------------- GEMM 256x256 8-phase (T2+T3+T4+T5): qkv, fc, proj(K-split) ----
#define SWZ9(x) ((x) ^ ((((x) >> 9) & 1) << 5))

#define RD_A(BUF, QM)                                                          \
  {                                                                            \
    const char* sb_ = smem + (((BUF)*2 + 0) * 2 + (QM)) * 16384;               \
    _Pragma("unroll") for (int i_ = 0; i_ < 4; i_++)                           \
    _Pragma("unroll") for (int kc_ = 0; kc_ < 2; kc_++) {                      \
      int x_ = kc_ * 8192 + (wr * 64 + i_ * 16 + ln) * 64 + kg * 16;           \
      Af[i_][kc_] = *(const bf16x8*)(sb_ + SWZ9(x_));                          \
    }                                                                          \
  }

#define RD_B(BUF, QN, BARR)                                                    \
  {                                                                            \
    const char* sb_ = smem + (((BUF)*2 + 1) * 2 + (QN)) * 16384;               \
    _Pragma("unroll") for (int j_ = 0; j_ < 2; j_++)                           \
    _Pragma("unroll") for (int kc_ = 0; kc_ < 2; kc_++) {                      \
      int x_ = kc_ * 8192 + (wc * 32 + j_ * 16 + ln) * 64 + kg * 16;           \
      BARR[j_][kc_] = *(const bf16x8*)(sb_ + SWZ9(x_));                        \
    }                                                                          \
  }

#define MFMAQ(QM, QN, BARR)                                                    \
  _Pragma("unroll") for (int i_ = 0; i_ < 4; i_++)                             \
  _Pragma("unroll") for (int j_ = 0; j_ < 2; j_++)                             \
  _Pragma("unroll") for (int kc_ = 0; kc_ < 2; kc_++)                          \
    acc[QM][QN][i_][j_] = __builtin_amdgcn_mfma_f32_16x16x32_bf16(             \
        Af[i_][kc_], BARR[j_][kc_], acc[QM][QN][i_][j_], 0, 0, 0);

#define PHTAIL()                                                               \
  __builtin_amdgcn_s_barrier();                                                \
  asm volatile("s_waitcnt lgkmcnt(0)" ::: "memory");                           \
  __builtin_amdgcn_sched_barrier(0);                                           \
  __builtin_amdgcn_s_setprio(1)

#define PHEND()                                                                \
  __builtin_amdgcn_s_setprio(0);                                               \
  __builtin_amdgcn_s_barrier()

template<int EPI, bool KSPLIT4>
__global__ __launch_bounds__(512, 2)
void gemm256(const unsigned short* __restrict__ A,
             const unsigned short* __restrict__ Bt,
             void* __restrict__ Cout,
             int M, int N, int Kfull, int Klen, int nInner,
             unsigned short* __restrict__ o1, unsigned short* __restrict__ o2,
             unsigned short* __restrict__ o3) {
  extern __shared__ char smem[];
  const int tid = threadIdx.x;
  const int wid = tid >> 6, lane = tid & 63;
  const int wr = wid >> 2, wc = wid & 3;
  const int ln = lane & 15, kg = lane >> 4;
  int blkid = (int)blockIdx.x;
  int split = 0;
  if constexpr (KSPLIT4) {
    split = blkid / nInner;
    blkid -= split * nInner;
  }
  const int nbm = M >> 8;
  const int xcd = blkid & 7, rr = blkid >> 3;
  const int slab = nbm >> 3;
  const int bm = xcd * slab + (rr % slab);
  const int bn = rr / slab;
  const int m0 = bm << 8, n0 = bn << 8;
  const size_t K2 = (size_t)Kfull * 2;
  const size_t kb0 = (size_t)split * Klen * 2;
  const char* Ac = (const char*)A;
  const char* Bc = (const char*)Bt;

  f32x4 acc[2][2][4][2] = {};
  bf16x8 Af[4][2], B0[2][2], B1[2][2];

  auto STG = [&](int buf, int ab, int h, int tile) {
    const char* gb = ab ? Bc : Ac;
    const int ro = (ab ? n0 : m0) + h * 128;
    char* db = smem + ((buf * 2 + ab) * 2 + h) * 16384;
#pragma unroll
    for (int q = 0; q < 2; q++) {
      const int p0 = q * 8192 + tid * 16;
      const int lin = SWZ9(p0);
      GLOAD_LDS(gb + (size_t)(ro + ((lin >> 6) & 127)) * K2 + kb0 +
                    (size_t)tile * 128 + (lin >> 13) * 64 + (lin & 63),
                db + p0);
    }
  };

  STG(0, 0, 0, 0); STG(0, 0, 1, 0); STG(0, 1, 0, 0); STG(0, 1, 1, 0);
  STG(1, 0, 0, 1); STG(1, 1, 0, 1); STG(1, 1, 1, 1);
  asm volatile("s_waitcnt vmcnt(6)" ::: "memory");
  __builtin_amdgcn_s_barrier();

  const int niter = Klen >> 7;   // pairs of 64-wide K-tiles
  for (int it = 0; it < niter; it++) {
    const int tA = 2 * it, tB = tA + 1;
    const bool more = (it + 1 < niter);

    RD_A(0, 0); RD_B(0, 0, B0);
    STG(1, 0, 1, tB);
    PHTAIL(); MFMAQ(0, 0, B0); PHEND();
    RD_B(0, 1, B1);
    if (more) STG(0, 0, 0, tA + 2);
    PHTAIL(); MFMAQ(0, 1, B1); PHEND();
    RD_A(0, 1);
    if (more) STG(0, 1, 0, tA + 2);
    PHTAIL(); MFMAQ(1, 0, B0); PHEND();
    if (more) {
      STG(0, 1, 1, tA + 2);
      asm volatile("s_waitcnt vmcnt(6)" ::: "memory");
    } else {
      asm volatile("s_waitcnt vmcnt(0)" ::: "memory");
    }
    PHTAIL(); MFMAQ(1, 1, B1); PHEND();
    RD_A(1, 0); RD_B(1, 0, B0);
    if (more) STG(0, 0, 1, tA + 2);
    PHTAIL(); MFMAQ(0, 0, B0); PHEND();
    RD_B(1, 1, B1);
    if (more) STG(1, 0, 0, tB + 2);
    PHTAIL(); MFMAQ(0, 1, B1); PHEND();
    RD_A(1, 1);
    if (more) STG(1, 1, 0, tB + 2);
    PHTAIL(); MFMAQ(1, 0, B0); PHEND();
    if (more) {
      STG(1, 1, 1, tB + 2);
      asm volatile("s_waitcnt vmcnt(6)" ::: "memory");
    }
    PHTAIL(); MFMAQ(1, 1, B1); PHEND();
  }

  unsigned short* bout = (unsigned short*)Cout;
  if constexpr (KSPLIT4) {
    if (split == 1) bout = o1;
    else if (split == 2) bout = o2;
    else if (split == 3) bout = o3;
  }

#pragma unroll
  for (int qm = 0; qm < 2; qm++)
#pragma unroll
    for (int qn = 0; qn < 2; qn++)
#pragma unroll
      for (int i = 0; i < 4; i++)
#pragma unroll
        for (int j = 0; j < 2; j++)
#pragma unroll
          for (int r = 0; r < 4; r++) {
            const int row = m0 + qm * 128 + wr * 64 + i * 16 + kg * 4 + r;
            const int col = n0 + qn * 128 + wc * 32 + j * 16 + ln;
            const size_t idx = (size_t)row * N + col;
            float v = acc[qm][qn][i][j][r];
            if (EPI == 2) {
              v = fmaxf(v, 0.0f);
              ((unsigned short*)Cout)[idx] = f2bf(v * v);
            } else if (EPI == 3) {
              ((unsigned short*)Cout)[idx] = f2bf(v);
            } else {
              bout[idx] = f2bf(v);      // bf16 K-split partial
            }
          }
}

// ---------------- RoPE + RMSNorm + v-mix (qkv in bf16) ----------------
__global__ __launch_bounds__(256)
void rope_rms_kernel(const unsigned short* __restrict__ qkv,
                     const float* __restrict__ ct, const float* __restrict__ st,
                     const float* __restrict__ ve, const float* __restrict__ salam,
                     unsigned short* __restrict__ Qh, unsigned short* __restrict__ Kh,
                     unsigned short* __restrict__ Vt) {
  const int t = threadIdx.x;
  const int wid = t >> 6, i = t & 63;
  const int g = blockIdx.x * 4 + wid;      // (b,s,h)
  const int b = g >> 14;
  const int s = (g >> 3) & 2047;
  const int h = g & 7;
  const unsigned short* base = qkv + (size_t)(b * 2048 + s) * 3072 + h * 128;
  float c = 1.0f, sn = 0.0f;
  if (i < 32) { c = ct[s * 32 + i]; sn = st[s * 32 + i]; }
  const float q1 = bf2f(base[i]), q2 = bf2f(base[64 + i]);
  const float k1 = bf2f(base[1024 + i]), k2 = bf2f(base[1024 + 64 + i]);
  const float q1r = q1 * c + q2 * sn, q2r = q2 * c - q1 * sn;
  const float k1r = k1 * c + k2 * sn, k2r = k2 * c - k1 * sn;
  float sq = q1r * q1r + q2r * q2r;
  float sk = k1r * k1r + k2r * k2r;
#pragma unroll
  for (int off = 1; off < 64; off <<= 1) {
    sq += __shfl_xor(sq, off);
    sk += __shfl_xor(sk, off);
  }
  const float eps = 1.1920929e-7f;
  const float rq = rsqrtf(sq * (1.0f / 128.0f) + eps);
  const float rk = rsqrtf(sk * (1.0f / 128.0f) + eps);
  unsigned short* qp = Qh + (((size_t)(b * 2048 + s) * 8 + h) << 7);
  unsigned short* kp = Kh + (((size_t)(b * 2048 + s) * 8 + h) << 7);
  qp[i] = f2bf(q1r * rq); qp[64 + i] = f2bf(q2r * rq);
  kp[i] = f2bf(k1r * rk); kp[64 + i] = f2bf(k2r * rk);
  const float l0 = salam[0], l1 = salam[1];
  const float* vep = ve + (size_t)s * 1024 + h * 128;
  const float v1 = l0 * bf2f(base[2048 + i]) + l1 * vep[i];
  const float v2 = l0 * bf2f(base[2048 + 64 + i]) + l1 * vep[64 + i];
  unsigned short* vp = Vt + (((size_t)(b * 8 + h) * 128) << 11) + s;
  vp[(size_t)i << 11] = f2bf(v1);
  vp[(size_t)(64 + i) << 11] = f2bf(v2);
}

// ---------------- flash attention, doc-causal (equal-work blocks) ----------------
// block = (pair pid, bh); processes qt=pid then qt=31-pid sequentially ->
// constant 66 KV-tiles/block. 8 waves: qw=wid&1 (32 q), kw=wid>>1 (4-way KV
// split). 128KB LDS -> 1 blk/CU, 8 waves live throughout.
__global__ __launch_bounds__(512, 2)
void attn_kernel(const unsigned short* __restrict__ Qh,
                 const unsigned short* __restrict__ Kh,
                 const unsigned short* __restrict__ Vt,
                 const int* __restrict__ qstart,
                 unsigned short* __restrict__ Out) {
  extern __shared__ char asmem[];   // 128KB: K [4 kw][2 buf][8KB] @0; V same @65536

  const int blk = blockIdx.x;        // 256 blocks
  const int pid = blk >> 4;          // 0..15
  const int bh = blk & 15;
  const int b = bh >> 3, h = bh & 7;
  const int t = threadIdx.x;
  const int wid = t >> 6, lane = t & 63;
  const int qw = wid & 1, kw = wid >> 1;    // kw 0..3
  const int ln5 = lane & 31, hi = lane >> 5;
  const int tp = qw * 64 + lane;            // staging tid within kw-group
  const float SC = 0.12f * 1.4426950408889634f;

  char* Kb = asmem + kw * 16384;
  char* Vb = asmem + 65536 + kw * 16384;

  const char* ksrc[4];
  const char* vsrc[4];
  char* kdst[4];
  char* vdst[4];
#pragma unroll
  for (int r = 0; r < 4; r++) {
    {
      const int e = tp * 16 + r * 2048;
      const int row = e >> 8;
      const int ch = (e >> 4) & 15;
      const int sch = ch ^ ((row ^ (row >> 3)) & 7);
      ksrc[r] = (const char*)(Kh + (((size_t)(b * 2048 + row) * 8 + h) << 7) + sch * 8);
      kdst[r] = Kb + r * 2048 + qw * 1024 + (lane << 4);
    }
    {
      const int e = tp * 16 + r * 2048;
      const int row = e >> 6;
      const int ch = (e >> 4) & 3;
      const int sch = ch ^ ((row >> 1) & 3);
      vsrc[r] = (const char*)(Vt + (((size_t)((b * 8 + h) * 128 + row)) << 11) + sch * 8);
      vdst[r] = Vb + r * 2048 + qw * 1024 + (lane << 4);
    }
  }

  auto STAGE = [&](int bb, int kt) {
    const size_t kof = (size_t)kt * 2048;
    const size_t vof = (size_t)kt * 2;
#pragma unroll
    for (int r = 0; r < 4; r++)
      GLOAD_LDS(ksrc[r] + kof, kdst[r] + bb * 8192);
#pragma unroll
    for (int r = 0; r < 4; r++)
      GLOAD_LDS(vsrc[r] + vof, vdst[r] + bb * 8192);
  };

  for (int ph = 0; ph < 2; ph++) {
    const int qt = ph ? (31 - pid) : pid;
    const int q0 = qt << 6;
    const int qrow = q0 + qw * 32;

    bf16x8 qf[8];
    {
      const unsigned short* qp =
          Qh + (((size_t)(b * 2048 + qrow + ln5) * 8 + h) << 7) + hi * 8;
#pragma unroll
      for (int c = 0; c < 8; c++) qf[c] = *(const bf16x8*)(qp + c * 16);
    }
    const int qid = qrow + ln5;
    const int qs = qstart[qid];
    int qsmax = qs;
#pragma unroll
    for (int off = 1; off < 32; off <<= 1)
      qsmax = max(qsmax, __shfl_xor(qsmax, off));

    float m = -64.0f, l = 0.0f;
    f32x16 o[4] = {};

    const int kt0 = qstart[q0] & ~31;
    const int T = (q0 + 64 - kt0) >> 5;

    __syncthreads();
    STAGE(0, kt0 + kw * 32);
    int cur = 0;
    const int nLoop = (T + 3) >> 2;

    for (int i = 0; i < nLoop; i++) {
      const int tid2 = 4 * i + kw;
      const bool hasnext = (tid2 + 4) < T;
      if (hasnext) {
        STAGE(cur ^ 1, kt0 + (tid2 + 4) * 32);
        asm volatile("s_waitcnt vmcnt(8)" ::: "memory");
      } else {
        asm volatile("s_waitcnt vmcnt(0)" ::: "memory");
      }
      __builtin_amdgcn_s_barrier();

      if (tid2 < T) {
        const int kt = kt0 + tid2 * 32;
        const unsigned short* ksb = (const unsigned short*)(Kb + cur * 8192);
        const unsigned short* vsb = (const unsigned short*)(Vb + cur * 8192);

        f32x16 sacc = {};
        {
          const int key = ln5;
          const int kx = (key ^ (key >> 3)) & 7;
          const unsigned short* krow = &ksb[key * 128];
#pragma unroll
          for (int c = 0; c < 8; c++) {
            bf16x8 kf = *(const bf16x8*)(krow + (((2 * c + hi) ^ kx) << 3));
            sacc = __builtin_amdgcn_mfma_f32_32x32x16_bf16(kf, qf[c], sacc, 0, 0, 0);
          }
        }

        const bool full = (kt + 32 <= qrow) && (kt >= qsmax);

        float p[16];
        float mx = -1e30f;
        if (full) {
#pragma unroll
          for (int i2 = 0; i2 < 16; i2++) {
            const float ts = sacc[i2] * SC;
            p[i2] = ts;
            mx = fmaxf(mx, ts);
          }
        } else {
#pragma unroll
          for (int i2 = 0; i2 < 16; i2++) {
            const int key = kt + (i2 & 3) + 8 * (i2 >> 2) + 4 * hi;
            const bool valid = (key <= qid) && (key >= qs);
            const float ts = valid ? sacc[i2] * SC : -1e30f;
            p[i2] = ts;
            mx = fmaxf(mx, ts);
          }
        }
        mx = fmaxf(mx, __shfl_xor(mx, 32));

        const bool dresc = __any(mx - m > 8.0f);
        if (dresc) {
          const float mn = fmaxf(m, mx);
          const float fac = exp2f(m - mn);
          m = mn;
          l *= fac;
#pragma unroll
          for (int r = 0; r < 16; r++) {
            const float fr = __shfl(fac, (r & 3) + 8 * (r >> 2) + 4 * hi);
            o[0][r] *= fr; o[1][r] *= fr; o[2][r] *= fr; o[3][r] *= fr;
          }
        }

        float sum = 0.0f;
#pragma unroll
        for (int i2 = 0; i2 < 16; i2++) {
          const float pv = exp2f(p[i2] - m);
          p[i2] = pv;
          sum += pv;
        }
        sum += __shfl_xor(sum, 32);
        l += sum;

        bf16x8 pa[2];
#pragma unroll
        for (int bb2 = 0; bb2 < 2; bb2++) {
          unsigned int a0 = cvtpk(p[bb2 * 8 + 0], p[bb2 * 8 + 1]);
          unsigned int b0 = cvtpk(p[bb2 * 8 + 4], p[bb2 * 8 + 5]);
          unsigned int a1 = cvtpk(p[bb2 * 8 + 2], p[bb2 * 8 + 3]);
          unsigned int b1 = cvtpk(p[bb2 * 8 + 6], p[bb2 * 8 + 7]);
          plswap(a0, b0);
          plswap(a1, b1);
          U8 u; u.u[0] = a0; u.u[1] = a1; u.u[2] = b0; u.u[3] = b1;
          pa[bb2] = u.v;
        }

#pragma unroll
        for (int dt = 0; dt < 4; dt++) {
          const int d = dt * 32 + ln5;
          const int dx = (d >> 1) & 3;
          const unsigned short* vrow = &vsb[d * 32];
#pragma unroll
          for (int ks = 0; ks < 2; ks++) {
            bf16x8 vf = *(const bf16x8*)(vrow + (((2 * ks + hi) ^ dx) << 3));
            o[dt] = __builtin_amdgcn_mfma_f32_32x32x16_bf16(pa[ks], vf, o[dt], 0, 0, 0);
          }
        }
      }

      __builtin_amdgcn_s_barrier();
      cur ^= 1;
    }

    // ---- 4-way merge through (now idle) LDS ----
    __syncthreads();
    float* oex = (float*)asmem;                 // [3][2 qw][64 lanes][65]
    float* mlx = (float*)(asmem + 99840);       // [3][2][32][2]
    if (kw != 0) {
      if (lane < 32) {
        mlx[(((kw - 1) * 2 + qw) * 32 + lane) * 2 + 0] = m;
        mlx[(((kw - 1) * 2 + qw) * 32 + lane) * 2 + 1] = l;
      }
      float* dst = oex + (((kw - 1) * 2 + qw) * 64 + lane) * 65;
#pragma unroll
      for (int dt = 0; dt < 4; dt++)
#pragma unroll
        for (int r = 0; r < 16; r++) dst[dt * 16 + r] = o[dt][r];
    }
    __syncthreads();
    if (kw == 0) {
      float mm[3], ll[3];
#pragma unroll
      for (int j = 0; j < 3; j++) {
        mm[j] = mlx[((j * 2 + qw) * 32 + ln5) * 2 + 0];
        ll[j] = mlx[((j * 2 + qw) * 32 + ln5) * 2 + 1];
      }
      const float ms = fmaxf(fmaxf(m, mm[0]), fmaxf(mm[1], mm[2]));
      const float a0 = exp2f(m - ms);
      const float a1 = exp2f(mm[0] - ms);
      const float a2 = exp2f(mm[1] - ms);
      const float a3 = exp2f(mm[2] - ms);
      const float inv = 1.0f / (l * a0 + ll[0] * a1 + ll[1] * a2 + ll[2] * a3);
      const float* s1 = oex + ((0 * 2 + qw) * 64 + lane) * 65;
      const float* s2 = oex + ((1 * 2 + qw) * 64 + lane) * 65;
      const float* s3 = oex + ((2 * 2 + qw) * 64 + lane) * 65;
#pragma unroll
      for (int r = 0; r < 16; r++) {
        const int crow = (r & 3) + 8 * (r >> 2) + 4 * hi;
        const float a0r = __shfl(a0, crow);
        const float a1r = __shfl(a1, crow);
        const float a2r = __shfl(a2, crow);
        const float a3r = __shfl(a3, crow);
        const float ivr = __shfl(inv, crow);
        const int q = qrow + crow;
        unsigned short* op = Out + (((size_t)(b * 2048 + q)) << 10) + h * 128 + ln5;
#pragma unroll
        for (int dt = 0; dt < 4; dt++)
          op[dt * 32] = f2bf((o[dt][r] * a0r + s1[dt * 16 + r] * a1r +
                              s2[dt * 16 + r] * a2r + s3[dt * 16 + r] * a3r) * ivr);
      }
    }
  }
}

// ---------------- launcher ----------------
extern "C" void kernel_launch(void* const* d_in, const int* in_sizes, int n_in,
                              void* d_out, int out_size, void* d_ws, size_t ws_size,
                              hipStream_t stream) {
  const float* x     = (const float*)d_in[0];
  const float* vemb  = (const float*)d_in[1];
  const float* x0    = (const float*)d_in[2];
  const float* lam   = (const float*)d_in[3];
  const float* slam  = (const float*)d_in[4];
  const float* ln1w  = (const float*)d_in[5];
  const float* ln2w  = (const float*)d_in[6];
  const float* wqkv  = (const float*)d_in[7];
  const float* wo    = (const float*)d_in[8];
  const float* wfc   = (const float*)d_in[9];
  const float* wproj = (const float*)d_in[10];
  const int*   ids   = (const int*)d_in[11];

  char* ws = (char*)d_ws;
  unsigned short* wqkvT  = (unsigned short*)(ws + 0);          //  6 MB
  unsigned short* woT    = (unsigned short*)(ws + 6291456);    //  2 MB
  unsigned short* wfcT   = (unsigned short*)(ws + 8388608);    //  8 MB
  unsigned short* wprojT = (unsigned short*)(ws + 16777216);   //  8 MB
  float*          xm     = (float*)(ws + 25165824);            // 16 MB
  unsigned short* qkv    = (unsigned short*)(ws + 41943040);   // 24 MB (bf16)
  unsigned short* hbuf   = (unsigned short*)(ws + 41943040);   // reuse (32 MB)
  unsigned short* xn1    = (unsigned short*)(ws + 92274688);   //  8 MB
  unsigned short* ao     = (unsigned short*)(ws + 92274688);   // reuse
  unsigned short* qh     = (unsigned short*)(ws + 100663296);  //  8 MB
  unsigned short* xn2    = (unsigned short*)(ws + 100663296);  // reuse
  unsigned short* kh     = (unsigned short*)(ws + 109051904);  //  8 MB
  unsigned short* vt     = (unsigned short*)(ws + 117440512);  //  8 MB
  float*          x2     = (float*)(ws + 109051904);           // reuse kh+vt (16 MB)
  float*          ctab   = (float*)(ws + 125829120);
  float*          stab   = (float*)(ws + 126091264);
  int*            qstart = (int*)(ws + 126353408);
  // bf16 K-split partials (8 MB each, all regions dead at proj time):
  unsigned short* P0 = (unsigned short*)(ws + 0);          // wqkvT+woT
  unsigned short* P1 = (unsigned short*)(ws + 8388608);    // wfcT (dead after fc)
  unsigned short* P2 = (unsigned short*)(ws + 25165824);   // xm lower half (dead after wo)
  unsigned short* P3 = (unsigned short*)(ws + 33554432);   // xm upper half

  static int attr_done = 0;
  if (!attr_done) {
    hipFuncSetAttribute((const void*)gemm256<3, false>,
                        hipFuncAttributeMaxDynamicSharedMemorySize, 131072);
    hipFuncSetAttribute((const void*)gemm256<2, false>,
                        hipFuncAttributeMaxDynamicSharedMemorySize, 131072);
    hipFuncSetAttribute((const void*)gemm256<4, true>,
                        hipFuncAttributeMaxDynamicSharedMemorySize, 131072);
    hipFuncSetAttribute((const void*)attn_kernel,
                        hipFuncAttributeMaxDynamicSharedMemorySize, 131072);
    attr_done = 1;
  }

  prep_kernel<<<dim3(257), dim3(256), 0, stream>>>(ctab, stab, ids, qstart);
  wtrans4_kernel<<<dim3(12288), dim3(256), 0, stream>>>(wqkv, wo, wfc, wproj,
                                                        wqkvT, woT, wfcT, wprojT);

  ln_kernel<true><<<dim3(4096), dim3(256), 0, stream>>>(x, x0, lam, ln1w, xm, xn1);
  gemm256<3, false><<<dim3(192), dim3(512), 131072, stream>>>(
      xn1, wqkvT, (void*)qkv, 4096, 3072, 1024, 1024, 0, nullptr, nullptr, nullptr);
  rope_rms_kernel<<<dim3(8192), dim3(256), 0, stream>>>(qkv, ctab, stab, vemb, slam, qh, kh, vt);
  attn_kernel<<<dim3(256), dim3(512), 131072, stream>>>(qh, kh, vt, qstart, ao);
  gemm_bt<1, 64, 64><<<dim3(64 * 8), dim3(256), 0, stream>>>(ao, woT, (void*)x2, xm,
                                                             4096, 1024, 1024);
  ln_kernel<false><<<dim3(4096), dim3(256), 0, stream>>>(x2, (const float*)nullptr,
                                                         (const float*)nullptr, ln2w,
                                                         (float*)nullptr, xn2);
  gemm256<2, false><<<dim3(256), dim3(512), 131072, stream>>>(
      xn2, wfcT, (void*)hbuf, 4096, 4096, 1024, 1024, 0, nullptr, nullptr, nullptr);
  gemm256<4, true><<<dim3(256), dim3(512), 131072, stream>>>(
      hbuf, wprojT, (void*)P0, 4096, 1024, 4096, 1024, 64, P1, P2, P3);
  add5_kernel<<<dim3(4096), dim3(256), 0, stream>>>(P0, P1, P2, P3, x2, (float*)d_out);
}

// Round 21
// 240.631 us; speedup vs baseline: 1.0542x; 1.0005x over previous
//
#include <hip/hip_runtime.h>

#define EOT_ID 50256

typedef __attribute__((ext_vector_type(8))) short bf16x8;
typedef __attribute__((ext_vector_type(4))) float f32x4;
typedef __attribute__((ext_vector_type(16))) float f32x16;

#define GLOAD_LDS(g, l)                                                        \
  __builtin_amdgcn_global_load_lds(                                            \
      (const __attribute__((address_space(1))) unsigned int*)(g),              \
      (__attribute__((address_space(3))) unsigned int*)(l), 16, 0, 0)

__device__ __forceinline__ unsigned short f2bf(float f) {
  union { float f; unsigned int u; } v; v.f = f;
  unsigned int r = v.u + 0x7FFFu + ((v.u >> 16) & 1u);
  return (unsigned short)(r >> 16);
}
__device__ __forceinline__ float bf2f(unsigned short b) {
  union { unsigned int u; float f; } v; v.u = ((unsigned int)b) << 16;
  return v.f;
}
__device__ __forceinline__ unsigned int cvtpk(float lo, float hi) {
  unsigned int r;
  asm("v_cvt_pk_bf16_f32 %0, %1, %2" : "=v"(r) : "v"(lo), "v"(hi));
  return r;
}
__device__ __forceinline__ void plswap(unsigned int& a, unsigned int& b) {
  asm volatile("v_permlane32_swap_b32 %0, %1" : "+v"(a), "+v"(b));
}
union U8 { unsigned int u[4]; bf16x8 v; };

// ---------------- prep: RoPE tables (blocks 0..255) + doc-scan (block 256) ----
__global__ __launch_bounds__(256)
void prep_kernel(float* __restrict__ ct, float* __restrict__ st,
                 const int* __restrict__ ids, int* __restrict__ qstart) {
  if (blockIdx.x < 256) {
    const int idx = blockIdx.x * 256 + threadIdx.x;   // 65536
    const int s = idx >> 5, i = idx & 31;
    const float ang = (float)s * exp2f(-10.0f * (float)i / 31.0f);
    float sv, cv;
    sincosf(ang, &sv, &cv);
    ct[idx] = cv;
    st[idx] = sv;
  } else {
    __shared__ int a[2048], b2[2048];
    const int t = threadIdx.x;
    for (int i = t; i < 2048; i += 256)
      a[i] = (ids[i] == EOT_ID) ? i : 0;
    __syncthreads();
    int* cur = a; int* nxt = b2;
    for (int off = 1; off < 2048; off <<= 1) {
      for (int i = t; i < 2048; i += 256) {
        int v = cur[i];
        if (i >= off) { int u = cur[i - off]; v = (u > v) ? u : v; }
        nxt[i] = v;
      }
      __syncthreads();
      int* tmp = cur; cur = nxt; nxt = tmp;
    }
    for (int i = t; i < 2048; i += 256) qstart[i] = cur[i];
  }
}

// ---------------- merged weight transpose f32 [K][N] -> bf16 [N][K] ----------------
__global__ __launch_bounds__(256)
void wtrans4_kernel(const float* __restrict__ wqkv, const float* __restrict__ wo,
                    const float* __restrict__ wfc, const float* __restrict__ wproj,
                    unsigned short* __restrict__ wqkvT, unsigned short* __restrict__ woT,
                    unsigned short* __restrict__ wfcT, unsigned short* __restrict__ wprojT) {
  int blk = blockIdx.x;
  const float* in;
  unsigned short* out;
  int K, N;
  if (blk < 3072)      { in = wqkv;  out = wqkvT;  K = 1024; N = 3072; }
  else if (blk < 4096) { blk -= 3072; in = wo;    out = woT;    K = 1024; N = 1024; }
  else if (blk < 8192) { blk -= 4096; in = wfc;   out = wfcT;   K = 1024; N = 4096; }
  else                 { blk -= 8192; in = wproj; out = wprojT; K = 4096; N = 1024; }
  __shared__ float tile[32][33];
  const int nb = N >> 5;
  const int k0 = (blk / nb) << 5, n0 = (blk % nb) << 5;
  const int tx = threadIdx.x & 31, ty = threadIdx.x >> 5;
#pragma unroll
  for (int p = 0; p < 4; p++)
    tile[ty + p * 8][tx] = in[(size_t)(k0 + ty + p * 8) * N + n0 + tx];
  __syncthreads();
#pragma unroll
  for (int p = 0; p < 4; p++)
    out[(size_t)(n0 + ty + p * 8) * K + k0 + tx] = f2bf(tile[tx][ty + p * 8]);
}

// ---------------- K-split reduce: out = bf16(p0+p1+p2+p3) + f32 res ----------------
__global__ __launch_bounds__(256)
void add5_kernel(const unsigned short* __restrict__ p0,
                 const unsigned short* __restrict__ p1,
                 const unsigned short* __restrict__ p2,
                 const unsigned short* __restrict__ p3,
                 const float* __restrict__ res, float* __restrict__ out) {
  const int i = (blockIdx.x * 256 + threadIdx.x) * 4;
  const ushort4 a = *(const ushort4*)(p0 + i);
  const ushort4 b = *(const ushort4*)(p1 + i);
  const ushort4 c = *(const ushort4*)(p2 + i);
  const ushort4 d = *(const ushort4*)(p3 + i);
  float4 e = *(const float4*)(res + i);
  e.x += bf2f(a.x) + bf2f(b.x) + bf2f(c.x) + bf2f(d.x);
  e.y += bf2f(a.y) + bf2f(b.y) + bf2f(c.y) + bf2f(d.y);
  e.z += bf2f(a.z) + bf2f(b.z) + bf2f(c.z) + bf2f(d.z);
  e.w += bf2f(a.w) + bf2f(b.w) + bf2f(c.w) + bf2f(d.w);
  *(float4*)(out + i) = e;
}

// ---------------- LayerNorm (optional residual mix) ----------------
template<bool MIX>
__global__ __launch_bounds__(256)
void ln_kernel(const float* __restrict__ x, const float* __restrict__ x0,
               const float* __restrict__ lam, const float* __restrict__ w,
               float* __restrict__ xm, unsigned short* __restrict__ xn) {
  __shared__ float red[8];
  const int row = blockIdx.x, t = threadIdx.x;
  const size_t base = (size_t)row << 10;
  float4 v = *(const float4*)(x + base + t * 4);
  if (MIX) {
    const float l0 = lam[0], l1 = lam[1];
    const float4 v0 = *(const float4*)(x0 + base + t * 4);
    v.x = l0 * v.x + l1 * v0.x;
    v.y = l0 * v.y + l1 * v0.y;
    v.z = l0 * v.z + l1 * v0.z;
    v.w = l0 * v.w + l1 * v0.w;
    *(float4*)(xm + base + t * 4) = v;
  }
  float s = v.x + v.y + v.z + v.w;
  float q = v.x * v.x + v.y * v.y + v.z * v.z + v.w * v.w;
#pragma unroll
  for (int off = 1; off < 64; off <<= 1) {
    s += __shfl_xor(s, off);
    q += __shfl_xor(q, off);
  }
  const int wid = t >> 6;
  if ((t & 63) == 0) { red[wid] = s; red[4 + wid] = q; }
  __syncthreads();
  s = red[0] + red[1] + red[2] + red[3];
  q = red[4] + red[5] + red[6] + red[7];
  const float mu = s * (1.0f / 1024.0f);
  const float var = q * (1.0f / 1024.0f) - mu * mu;
  const float rstd = rsqrtf(var + 1e-6f);
  const float4 wv = *(const float4*)(w + t * 4);
  ushort4 u;
  u.x = f2bf((v.x - mu) * rstd * wv.x);
  u.y = f2bf((v.y - mu) * rstd * wv.y);
  u.z = f2bf((v.z - mu) * rstd * wv.z);
  u.w = f2bf((v.w - mu) * rstd * wv.w);
  *(ushort4*)(xn + base + t * 4) = u;
}

// ---------------- GEMM (128-tile, 2-phase): used for wo ----------------
template<int EPI, int BM, int BK>
__global__ __launch_bounds__(256, 4)
void gemm_bt(const unsigned short* __restrict__ A,
             const unsigned short* __restrict__ Bt,
             void* __restrict__ Cout,
             const float* __restrict__ res,
             int M, int N, int K) {
  __shared__ unsigned short As[2][BM * BK];
  __shared__ unsigned short Bs[2][128 * BK];
  const int t = threadIdx.x;
  const int wid = t >> 6;
  const int lane = t & 63;
  const int ln = lane & 15, kg = lane >> 4;
  const int nbm = M / BM;
  const int xcd = (int)blockIdx.x & 7, rr = (int)blockIdx.x >> 3;
  const int slab = nbm >> 3;
  const int bm = xcd * slab + (rr % slab);
  const int bn = rr / slab;
  const int m0 = bm * BM, n0 = bn << 7;
  const int wrow = (BM == 128) ? ((wid >> 1) * 64) : 0;
  const int wcol = (BM == 128) ? ((wid & 1) * 64) : (wid * 32);
  constexpr int NJ = (BM == 128) ? 4 : 2;
  constexpr int LA = BM * BK / 2048;
  constexpr int LB = 128 * BK / 2048;
  constexpr int KC = BK / 32;

  f32x4 acc[4][NJ] = {};

  const unsigned short* Abase = A + (size_t)m0 * K;
  const unsigned short* Bbase = Bt + (size_t)n0 * K;

  auto swz = [&](int row, int chunk) -> int {
    if constexpr (BK == 32) return chunk ^ ((row >> 1) & 3);
    else                    return chunk ^ (row & 7);
  };

  auto STAGE = [&](int bb, int kt) {
#pragma unroll
    for (int p = 0; p < LA; p++) {
      const int e = t * 8 + p * 2048;
      const int r = e / BK;
      const int cs = swz(r, (e >> 3) & (BK / 8 - 1));
      GLOAD_LDS(Abase + (size_t)r * K + kt + cs * 8, &As[bb][p * 2048 + wid * 512]);
    }
#pragma unroll
    for (int p = 0; p < LB; p++) {
      const int e = t * 8 + p * 2048;
      const int r = e / BK;
      const int cs = swz(r, (e >> 3) & (BK / 8 - 1));
      GLOAD_LDS(Bbase + (size_t)r * K + kt + cs * 8, &Bs[bb][p * 2048 + wid * 512]);
    }
  };

  STAGE(0, 0);
  int cur = 0;
  const int nk = K / BK;
  for (int ki = 0; ki < nk; ki++) {
    if (ki + 1 < nk) {
      STAGE(cur ^ 1, (ki + 1) * BK);
      if constexpr (LA + LB == 4)
        asm volatile("s_waitcnt vmcnt(4)" ::: "memory");
      else
        asm volatile("s_waitcnt vmcnt(6)" ::: "memory");
    } else {
      asm volatile("s_waitcnt vmcnt(0)" ::: "memory");
    }
    __builtin_amdgcn_s_barrier();

#pragma unroll
    for (int c = 0; c < KC; c++) {
      bf16x8 af[4], bfr[NJ];
#pragma unroll
      for (int i = 0; i < 4; i++) {
        const int ra = wrow + i * 16 + ln;
        af[i] = *(const bf16x8*)(&As[cur][ra * BK + swz(ra, c * 4 + kg) * 8]);
      }
#pragma unroll
      for (int j = 0; j < NJ; j++) {
        const int rb = wcol + j * 16 + ln;
        bfr[j] = *(const bf16x8*)(&Bs[cur][rb * BK + swz(rb, c * 4 + kg) * 8]);
      }
#pragma unroll
      for (int i = 0; i < 4; i++)
#pragma unroll
        for (int j = 0; j < NJ; j++)
          acc[i][j] = __builtin_amdgcn_mfma_f32_16x16x32_bf16(af[i], bfr[j], acc[i][j], 0, 0, 0);
    }

    __builtin_amdgcn_s_barrier();
    cur ^= 1;
  }

#pragma unroll
  for (int i = 0; i < 4; i++) {
#pragma unroll
    for (int j = 0; j < NJ; j++) {
#pragma unroll
      for (int r = 0; r < 4; r++) {
        const int row = m0 + wrow + i * 16 + kg * 4 + r;
        const int col = n0 + wcol + j * 16 + ln;
        const size_t idx = (size_t)row * N + col;
        float v = acc[i][j][r];
        if (EPI == 0) {
          ((float*)Cout)[idx] = v;
        } else if (EPI == 1) {
          ((float*)Cout)[idx] = v + res[idx];
        } else if (EPI == 2) {
          v = fmaxf(v, 0.0f);
          ((unsigned short*)Cout)[idx] = f2bf(v * v);
        } else {
          ((unsigned short*)Cout)[idx] = f2bf(v);
        }
      }
    }
  }
}

// ---------------- GEMM 256x256 8-phase (T2+T3+T4+T5): qkv, fc, proj(K-split) ----
#define SWZ9(x) ((x) ^ ((((x) >> 9) & 1) << 5))

#define RD_A(BUF, QM)                                                          \
  {                                                                            \
    const char* sb_ = smem + (((BUF)*2 + 0) * 2 + (QM)) * 16384;               \
    _Pragma("unroll") for (int i_ = 0; i_ < 4; i_++)                           \
    _Pragma("unroll") for (int kc_ = 0; kc_ < 2; kc_++) {                      \
      int x_ = kc_ * 8192 + (wr * 64 + i_ * 16 + ln) * 64 + kg * 16;           \
      Af[i_][kc_] = *(const bf16x8*)(sb_ + SWZ9(x_));                          \
    }                                                                          \
  }

#define RD_B(BUF, QN, BARR)                                                    \
  {                                                                            \
    const char* sb_ = smem + (((BUF)*2 + 1) * 2 + (QN)) * 16384;               \
    _Pragma("unroll") for (int j_ = 0; j_ < 2; j_++)                           \
    _Pragma("unroll") for (int kc_ = 0; kc_ < 2; kc_++) {                      \
      int x_ = kc_ * 8192 + (wc * 32 + j_ * 16 + ln) * 64 + kg * 16;           \
      BARR[j_][kc_] = *(const bf16x8*)(sb_ + SWZ9(x_));                        \
    }                                                                          \
  }

#define MFMAQ(QM, QN, BARR)                                                    \
  _Pragma("unroll") for (int i_ = 0; i_ < 4; i_++)                             \
  _Pragma("unroll") for (int j_ = 0; j_ < 2; j_++)                             \
  _Pragma("unroll") for (int kc_ = 0; kc_ < 2; kc_++)                          \
    acc[QM][QN][i_][j_] = __builtin_amdgcn_mfma_f32_16x16x32_bf16(             \
        Af[i_][kc_], BARR[j_][kc_], acc[QM][QN][i_][j_], 0, 0, 0);

#define PHTAIL()                                                               \
  __builtin_amdgcn_s_barrier();                                                \
  asm volatile("s_waitcnt lgkmcnt(0)" ::: "memory");                           \
  __builtin_amdgcn_sched_barrier(0);                                           \
  __builtin_amdgcn_s_setprio(1)

#define PHEND()                                                                \
  __builtin_amdgcn_s_setprio(0);                                               \
  __builtin_amdgcn_s_barrier()

template<int EPI, bool KSPLIT4>
__global__ __launch_bounds__(512, 2)
void gemm256(const unsigned short* __restrict__ A,
             const unsigned short* __restrict__ Bt,
             void* __restrict__ Cout,
             int M, int N, int Kfull, int Klen, int nInner,
             unsigned short* __restrict__ o1, unsigned short* __restrict__ o2,
             unsigned short* __restrict__ o3) {
  extern __shared__ char smem[];
  const int tid = threadIdx.x;
  const int wid = tid >> 6, lane = tid & 63;
  const int wr = wid >> 2, wc = wid & 3;
  const int ln = lane & 15, kg = lane >> 4;
  int blkid = (int)blockIdx.x;
  int split = 0;
  if constexpr (KSPLIT4) {
    split = blkid / nInner;
    blkid -= split * nInner;
  }
  const int nbm = M >> 8;
  const int xcd = blkid & 7, rr = blkid >> 3;
  const int slab = nbm >> 3;
  const int bm = xcd * slab + (rr % slab);
  const int bn = rr / slab;
  const int m0 = bm << 8, n0 = bn << 8;
  const size_t K2 = (size_t)Kfull * 2;
  const size_t kb0 = (size_t)split * Klen * 2;
  const char* Ac = (const char*)A;
  const char* Bc = (const char*)Bt;

  f32x4 acc[2][2][4][2] = {};
  bf16x8 Af[4][2], B0[2][2], B1[2][2];

  auto STG = [&](int buf, int ab, int h, int tile) {
    const char* gb = ab ? Bc : Ac;
    const int ro = (ab ? n0 : m0) + h * 128;
    char* db = smem + ((buf * 2 + ab) * 2 + h) * 16384;
#pragma unroll
    for (int q = 0; q < 2; q++) {
      const int p0 = q * 8192 + tid * 16;
      const int lin = SWZ9(p0);
      GLOAD_LDS(gb + (size_t)(ro + ((lin >> 6) & 127)) * K2 + kb0 +
                    (size_t)tile * 128 + (lin >> 13) * 64 + (lin & 63),
                db + p0);
    }
  };

  STG(0, 0, 0, 0); STG(0, 0, 1, 0); STG(0, 1, 0, 0); STG(0, 1, 1, 0);
  STG(1, 0, 0, 1); STG(1, 1, 0, 1); STG(1, 1, 1, 1);
  asm volatile("s_waitcnt vmcnt(6)" ::: "memory");
  __builtin_amdgcn_s_barrier();

  const int niter = Klen >> 7;   // pairs of 64-wide K-tiles
  for (int it = 0; it < niter; it++) {
    const int tA = 2 * it, tB = tA + 1;
    const bool more = (it + 1 < niter);

    RD_A(0, 0); RD_B(0, 0, B0);
    STG(1, 0, 1, tB);
    PHTAIL(); MFMAQ(0, 0, B0); PHEND();
    RD_B(0, 1, B1);
    if (more) STG(0, 0, 0, tA + 2);
    PHTAIL(); MFMAQ(0, 1, B1); PHEND();
    RD_A(0, 1);
    if (more) STG(0, 1, 0, tA + 2);
    PHTAIL(); MFMAQ(1, 0, B0); PHEND();
    if (more) {
      STG(0, 1, 1, tA + 2);
      asm volatile("s_waitcnt vmcnt(6)" ::: "memory");
    } else {
      asm volatile("s_waitcnt vmcnt(0)" ::: "memory");
    }
    PHTAIL(); MFMAQ(1, 1, B1); PHEND();
    RD_A(1, 0); RD_B(1, 0, B0);
    if (more) STG(0, 0, 1, tA + 2);
    PHTAIL(); MFMAQ(0, 0, B0); PHEND();
    RD_B(1, 1, B1);
    if (more) STG(1, 0, 0, tB + 2);
    PHTAIL(); MFMAQ(0, 1, B1); PHEND();
    RD_A(1, 1);
    if (more) STG(1, 1, 0, tB + 2);
    PHTAIL(); MFMAQ(1, 0, B0); PHEND();
    if (more) {
      STG(1, 1, 1, tB + 2);
      asm volatile("s_waitcnt vmcnt(6)" ::: "memory");
    }
    PHTAIL(); MFMAQ(1, 1, B1); PHEND();
  }

  unsigned short* bout = (unsigned short*)Cout;
  if constexpr (KSPLIT4) {
    if (split == 1) bout = o1;
    else if (split == 2) bout = o2;
    else if (split == 3) bout = o3;
  }

#pragma unroll
  for (int qm = 0; qm < 2; qm++)
#pragma unroll
    for (int qn = 0; qn < 2; qn++)
#pragma unroll
      for (int i = 0; i < 4; i++)
#pragma unroll
        for (int j = 0; j < 2; j++)
#pragma unroll
          for (int r = 0; r < 4; r++) {
            const int row = m0 + qm * 128 + wr * 64 + i * 16 + kg * 4 + r;
            const int col = n0 + qn * 128 + wc * 32 + j * 16 + ln;
            const size_t idx = (size_t)row * N + col;
            float v = acc[qm][qn][i][j][r];
            if (EPI == 2) {
              v = fmaxf(v, 0.0f);
              ((unsigned short*)Cout)[idx] = f2bf(v * v);
            } else if (EPI == 3) {
              ((unsigned short*)Cout)[idx] = f2bf(v);
            } else {
              bout[idx] = f2bf(v);      // bf16 K-split partial
            }
          }
}

// ---------------- RoPE + RMSNorm + v-mix (qkv in bf16) ----------------
__global__ __launch_bounds__(256)
void rope_rms_kernel(const unsigned short* __restrict__ qkv,
                     const float* __restrict__ ct, const float* __restrict__ st,
                     const float* __restrict__ ve, const float* __restrict__ salam,
                     unsigned short* __restrict__ Qh, unsigned short* __restrict__ Kh,
                     unsigned short* __restrict__ Vt) {
  const int t = threadIdx.x;
  const int wid = t >> 6, i = t & 63;
  const int g = blockIdx.x * 4 + wid;      // (b,s,h)
  const int b = g >> 14;
  const int s = (g >> 3) & 2047;
  const int h = g & 7;
  const unsigned short* base = qkv + (size_t)(b * 2048 + s) * 3072 + h * 128;
  float c = 1.0f, sn = 0.0f;
  if (i < 32) { c = ct[s * 32 + i]; sn = st[s * 32 + i]; }
  const float q1 = bf2f(base[i]), q2 = bf2f(base[64 + i]);
  const float k1 = bf2f(base[1024 + i]), k2 = bf2f(base[1024 + 64 + i]);
  const float q1r = q1 * c + q2 * sn, q2r = q2 * c - q1 * sn;
  const float k1r = k1 * c + k2 * sn, k2r = k2 * c - k1 * sn;
  float sq = q1r * q1r + q2r * q2r;
  float sk = k1r * k1r + k2r * k2r;
#pragma unroll
  for (int off = 1; off < 64; off <<= 1) {
    sq += __shfl_xor(sq, off);
    sk += __shfl_xor(sk, off);
  }
  const float eps = 1.1920929e-7f;
  const float rq = rsqrtf(sq * (1.0f / 128.0f) + eps);
  const float rk = rsqrtf(sk * (1.0f / 128.0f) + eps);
  unsigned short* qp = Qh + (((size_t)(b * 2048 + s) * 8 + h) << 7);
  unsigned short* kp = Kh + (((size_t)(b * 2048 + s) * 8 + h) << 7);
  qp[i] = f2bf(q1r * rq); qp[64 + i] = f2bf(q2r * rq);
  kp[i] = f2bf(k1r * rk); kp[64 + i] = f2bf(k2r * rk);
  const float l0 = salam[0], l1 = salam[1];
  const float* vep = ve + (size_t)s * 1024 + h * 128;
  const float v1 = l0 * bf2f(base[2048 + i]) + l1 * vep[i];
  const float v2 = l0 * bf2f(base[2048 + 64 + i]) + l1 * vep[64 + i];
  unsigned short* vp = Vt + (((size_t)(b * 8 + h) * 128) << 11) + s;
  vp[(size_t)i << 11] = f2bf(v1);
  vp[(size_t)(64 + i) << 11] = f2bf(v2);
}

// ---------------- flash attention, doc-causal (equal-work blocks + T5 setprio) ----
__global__ __launch_bounds__(512, 2)
void attn_kernel(const unsigned short* __restrict__ Qh,
                 const unsigned short* __restrict__ Kh,
                 const unsigned short* __restrict__ Vt,
                 const int* __restrict__ qstart,
                 unsigned short* __restrict__ Out) {
  extern __shared__ char asmem[];   // 128KB: K [4 kw][2 buf][8KB] @0; V same @65536

  const int blk = blockIdx.x;        // 256 blocks
  const int pid = blk >> 4;          // 0..15
  const int bh = blk & 15;
  const int b = bh >> 3, h = bh & 7;
  const int t = threadIdx.x;
  const int wid = t >> 6, lane = t & 63;
  const int qw = wid & 1, kw = wid >> 1;    // kw 0..3
  const int ln5 = lane & 31, hi = lane >> 5;
  const int tp = qw * 64 + lane;            // staging tid within kw-group
  const float SC = 0.12f * 1.4426950408889634f;

  char* Kb = asmem + kw * 16384;
  char* Vb = asmem + 65536 + kw * 16384;

  const char* ksrc[4];
  const char* vsrc[4];
  char* kdst[4];
  char* vdst[4];
#pragma unroll
  for (int r = 0; r < 4; r++) {
    {
      const int e = tp * 16 + r * 2048;
      const int row = e >> 8;
      const int ch = (e >> 4) & 15;
      const int sch = ch ^ ((row ^ (row >> 3)) & 7);
      ksrc[r] = (const char*)(Kh + (((size_t)(b * 2048 + row) * 8 + h) << 7) + sch * 8);
      kdst[r] = Kb + r * 2048 + qw * 1024 + (lane << 4);
    }
    {
      const int e = tp * 16 + r * 2048;
      const int row = e >> 6;
      const int ch = (e >> 4) & 3;
      const int sch = ch ^ ((row >> 1) & 3);
      vsrc[r] = (const char*)(Vt + (((size_t)((b * 8 + h) * 128 + row)) << 11) + sch * 8);
      vdst[r] = Vb + r * 2048 + qw * 1024 + (lane << 4);
    }
  }

  auto STAGE = [&](int bb, int kt) {
    const size_t kof = (size_t)kt * 2048;
    const size_t vof = (size_t)kt * 2;
#pragma unroll
    for (int r = 0; r < 4; r++)
      GLOAD_LDS(ksrc[r] + kof, kdst[r] + bb * 8192);
#pragma unroll
    for (int r = 0; r < 4; r++)
      GLOAD_LDS(vsrc[r] + vof, vdst[r] + bb * 8192);
  };

  for (int ph = 0; ph < 2; ph++) {
    const int qt = ph ? (31 - pid) : pid;
    const int q0 = qt << 6;
    const int qrow = q0 + qw * 32;

    bf16x8 qf[8];
    {
      const unsigned short* qp =
          Qh + (((size_t)(b * 2048 + qrow + ln5) * 8 + h) << 7) + hi * 8;
#pragma unroll
      for (int c = 0; c < 8; c++) qf[c] = *(const bf16x8*)(qp + c * 16);
    }
    const int qid = qrow + ln5;
    const int qs = qstart[qid];
    int qsmax = qs;
#pragma unroll
    for (int off = 1; off < 32; off <<= 1)
      qsmax = max(qsmax, __shfl_xor(qsmax, off));

    float m = -64.0f, l = 0.0f;
    f32x16 o[4] = {};

    const int kt0 = qstart[q0] & ~31;
    const int T = (q0 + 64 - kt0) >> 5;

    __syncthreads();
    STAGE(0, kt0 + kw * 32);
    int cur = 0;
    const int nLoop = (T + 3) >> 2;

    for (int i = 0; i < nLoop; i++) {
      const int tid2 = 4 * i + kw;
      const bool hasnext = (tid2 + 4) < T;
      if (hasnext) {
        STAGE(cur ^ 1, kt0 + (tid2 + 4) * 32);
        asm volatile("s_waitcnt vmcnt(8)" ::: "memory");
      } else {
        asm volatile("s_waitcnt vmcnt(0)" ::: "memory");
      }
      __builtin_amdgcn_s_barrier();

      if (tid2 < T) {
        const int kt = kt0 + tid2 * 32;
        const unsigned short* ksb = (const unsigned short*)(Kb + cur * 8192);
        const unsigned short* vsb = (const unsigned short*)(Vb + cur * 8192);

        f32x16 sacc = {};
        {
          const int key = ln5;
          const int kx = (key ^ (key >> 3)) & 7;
          const unsigned short* krow = &ksb[key * 128];
          __builtin_amdgcn_s_setprio(1);
#pragma unroll
          for (int c = 0; c < 8; c++) {
            bf16x8 kf = *(const bf16x8*)(krow + (((2 * c + hi) ^ kx) << 3));
            sacc = __builtin_amdgcn_mfma_f32_32x32x16_bf16(kf, qf[c], sacc, 0, 0, 0);
          }
          __builtin_amdgcn_s_setprio(0);
        }

        const bool full = (kt + 32 <= qrow) && (kt >= qsmax);

        float p[16];
        float mx = -1e30f;
        if (full) {
#pragma unroll
          for (int i2 = 0; i2 < 16; i2++) {
            const float ts = sacc[i2] * SC;
            p[i2] = ts;
            mx = fmaxf(mx, ts);
          }
        } else {
#pragma unroll
          for (int i2 = 0; i2 < 16; i2++) {
            const int key = kt + (i2 & 3) + 8 * (i2 >> 2) + 4 * hi;
            const bool valid = (key <= qid) && (key >= qs);
            const float ts = valid ? sacc[i2] * SC : -1e30f;
            p[i2] = ts;
            mx = fmaxf(mx, ts);
          }
        }
        mx = fmaxf(mx, __shfl_xor(mx, 32));

        const bool dresc = __any(mx - m > 8.0f);
        if (dresc) {
          const float mn = fmaxf(m, mx);
          const float fac = exp2f(m - mn);
          m = mn;
          l *= fac;
#pragma unroll
          for (int r = 0; r < 16; r++) {
            const float fr = __shfl(fac, (r & 3) + 8 * (r >> 2) + 4 * hi);
            o[0][r] *= fr; o[1][r] *= fr; o[2][r] *= fr; o[3][r] *= fr;
          }
        }

        float sum = 0.0f;
#pragma unroll
        for (int i2 = 0; i2 < 16; i2++) {
          const float pv = exp2f(p[i2] - m);
          p[i2] = pv;
          sum += pv;
        }
        sum += __shfl_xor(sum, 32);
        l += sum;

        bf16x8 pa[2];
#pragma unroll
        for (int bb2 = 0; bb2 < 2; bb2++) {
          unsigned int a0 = cvtpk(p[bb2 * 8 + 0], p[bb2 * 8 + 1]);
          unsigned int b0 = cvtpk(p[bb2 * 8 + 4], p[bb2 * 8 + 5]);
          unsigned int a1 = cvtpk(p[bb2 * 8 + 2], p[bb2 * 8 + 3]);
          unsigned int b1 = cvtpk(p[bb2 * 8 + 6], p[bb2 * 8 + 7]);
          plswap(a0, b0);
          plswap(a1, b1);
          U8 u; u.u[0] = a0; u.u[1] = a1; u.u[2] = b0; u.u[3] = b1;
          pa[bb2] = u.v;
        }

        __builtin_amdgcn_s_setprio(1);
#pragma unroll
        for (int dt = 0; dt < 4; dt++) {
          const int d = dt * 32 + ln5;
          const int dx = (d >> 1) & 3;
          const unsigned short* vrow = &vsb[d * 32];
#pragma unroll
          for (int ks = 0; ks < 2; ks++) {
            bf16x8 vf = *(const bf16x8*)(vrow + (((2 * ks + hi) ^ dx) << 3));
            o[dt] = __builtin_amdgcn_mfma_f32_32x32x16_bf16(pa[ks], vf, o[dt], 0, 0, 0);
          }
        }
        __builtin_amdgcn_s_setprio(0);
      }

      __builtin_amdgcn_s_barrier();
      cur ^= 1;
    }

    // ---- 4-way merge through (now idle) LDS ----
    __syncthreads();
    float* oex = (float*)asmem;                 // [3][2 qw][64 lanes][65]
    float* mlx = (float*)(asmem + 99840);       // [3][2][32][2]
    if (kw != 0) {
      if (lane < 32) {
        mlx[(((kw - 1) * 2 + qw) * 32 + lane) * 2 + 0] = m;
        mlx[(((kw - 1) * 2 + qw) * 32 + lane) * 2 + 1] = l;
      }
      float* dst = oex + (((kw - 1) * 2 + qw) * 64 + lane) * 65;
#pragma unroll
      for (int dt = 0; dt < 4; dt++)
#pragma unroll
        for (int r = 0; r < 16; r++) dst[dt * 16 + r] = o[dt][r];
    }
    __syncthreads();
    if (kw == 0) {
      float mm[3], ll[3];
#pragma unroll
      for (int j = 0; j < 3; j++) {
        mm[j] = mlx[((j * 2 + qw) * 32 + ln5) * 2 + 0];
        ll[j] = mlx[((j * 2 + qw) * 32 + ln5) * 2 + 1];
      }
      const float ms = fmaxf(fmaxf(m, mm[0]), fmaxf(mm[1], mm[2]));
      const float a0 = exp2f(m - ms);
      const float a1 = exp2f(mm[0] - ms);
      const float a2 = exp2f(mm[1] - ms);
      const float a3 = exp2f(mm[2] - ms);
      const float inv = 1.0f / (l * a0 + ll[0] * a1 + ll[1] * a2 + ll[2] * a3);
      const float* s1 = oex + ((0 * 2 + qw) * 64 + lane) * 65;
      const float* s2 = oex + ((1 * 2 + qw) * 64 + lane) * 65;
      const float* s3 = oex + ((2 * 2 + qw) * 64 + lane) * 65;
#pragma unroll
      for (int r = 0; r < 16; r++) {
        const int crow = (r & 3) + 8 * (r >> 2) + 4 * hi;
        const float a0r = __shfl(a0, crow);
        const float a1r = __shfl(a1, crow);
        const float a2r = __shfl(a2, crow);
        const float a3r = __shfl(a3, crow);
        const float ivr = __shfl(inv, crow);
        const int q = qrow + crow;
        unsigned short* op = Out + (((size_t)(b * 2048 + q)) << 10) + h * 128 + ln5;
#pragma unroll
        for (int dt = 0; dt < 4; dt++)
          op[dt * 32] = f2bf((o[dt][r] * a0r + s1[dt * 16 + r] * a1r +
                              s2[dt * 16 + r] * a2r + s3[dt * 16 + r] * a3r) * ivr);
      }
    }
  }
}

// ---------------- launcher ----------------
extern "C" void kernel_launch(void* const* d_in, const int* in_sizes, int n_in,
                              void* d_out, int out_size, void* d_ws, size_t ws_size,
                              hipStream_t stream) {
  const float* x     = (const float*)d_in[0];
  const float* vemb  = (const float*)d_in[1];
  const float* x0    = (const float*)d_in[2];
  const float* lam   = (const float*)d_in[3];
  const float* slam  = (const float*)d_in[4];
  const float* ln1w  = (const float*)d_in[5];
  const float* ln2w  = (const float*)d_in[6];
  const float* wqkv  = (const float*)d_in[7];
  const float* wo    = (const float*)d_in[8];
  const float* wfc   = (const float*)d_in[9];
  const float* wproj = (const float*)d_in[10];
  const int*   ids   = (const int*)d_in[11];

  char* ws = (char*)d_ws;
  unsigned short* wqkvT  = (unsigned short*)(ws + 0);          //  6 MB
  unsigned short* woT    = (unsigned short*)(ws + 6291456);    //  2 MB
  unsigned short* wfcT   = (unsigned short*)(ws + 8388608);    //  8 MB
  unsigned short* wprojT = (unsigned short*)(ws + 16777216);   //  8 MB
  float*          xm     = (float*)(ws + 25165824);            // 16 MB
  unsigned short* qkv    = (unsigned short*)(ws + 41943040);   // 24 MB (bf16)
  unsigned short* hbuf   = (unsigned short*)(ws + 41943040);   // reuse (32 MB)
  unsigned short* xn1    = (unsigned short*)(ws + 92274688);   //  8 MB
  unsigned short* ao     = (unsigned short*)(ws + 92274688);   // reuse
  unsigned short* qh     = (unsigned short*)(ws + 100663296);  //  8 MB
  unsigned short* xn2    = (unsigned short*)(ws + 100663296);  // reuse
  unsigned short* kh     = (unsigned short*)(ws + 109051904);  //  8 MB
  unsigned short* vt     = (unsigned short*)(ws + 117440512);  //  8 MB
  float*          x2     = (float*)(ws + 109051904);           // reuse kh+vt (16 MB)
  float*          ctab   = (float*)(ws + 125829120);
  float*          stab   = (float*)(ws + 126091264);
  int*            qstart = (int*)(ws + 126353408);
  // bf16 K-split partials (8 MB each, all regions dead at proj time):
  unsigned short* P0 = (unsigned short*)(ws + 0);          // wqkvT+woT
  unsigned short* P1 = (unsigned short*)(ws + 8388608);    // wfcT (dead after fc)
  unsigned short* P2 = (unsigned short*)(ws + 25165824);   // xm lower half (dead after wo)
  unsigned short* P3 = (unsigned short*)(ws + 33554432);   // xm upper half

  static int attr_done = 0;
  if (!attr_done) {
    hipFuncSetAttribute((const void*)gemm256<3, false>,
                        hipFuncAttributeMaxDynamicSharedMemorySize, 131072);
    hipFuncSetAttribute((const void*)gemm256<2, false>,
                        hipFuncAttributeMaxDynamicSharedMemorySize, 131072);
    hipFuncSetAttribute((const void*)gemm256<4, true>,
                        hipFuncAttributeMaxDynamicSharedMemorySize, 131072);
    hipFuncSetAttribute((const void*)attn_kernel,
                        hipFuncAttributeMaxDynamicSharedMemorySize, 131072);
    attr_done = 1;
  }

  prep_kernel<<<dim3(257), dim3(256), 0, stream>>>(ctab, stab, ids, qstart);
  wtrans4_kernel<<<dim3(12288), dim3(256), 0, stream>>>(wqkv, wo, wfc, wproj,
                                                        wqkvT, woT, wfcT, wprojT);

  ln_kernel<true><<<dim3(4096), dim3(256), 0, stream>>>(x, x0, lam, ln1w, xm, xn1);
  gemm256<3, false><<<dim3(192), dim3(512), 131072, stream>>>(
      xn1, wqkvT, (void*)qkv, 4096, 3072, 1024, 1024, 0, nullptr, nullptr, nullptr);
  rope_rms_kernel<<<dim3(8192), dim3(256), 0, stream>>>(qkv, ctab, stab, vemb, slam, qh, kh, vt);
  attn_kernel<<<dim3(256), dim3(512), 131072, stream>>>(qh, kh, vt, qstart, ao);
  gemm_bt<1, 64, 64><<<dim3(64 * 8), dim3(256), 0, stream>>>(ao, woT, (void*)x2, xm,
                                                             4096, 1024, 1024);
  ln_kernel<false><<<dim3(4096), dim3(256), 0, stream>>>(x2, (const float*)nullptr,
                                                         (const float*)nullptr, ln2w,
                                                         (float*)nullptr, xn2);
  gemm256<2, false><<<dim3(256), dim3(512), 131072, stream>>>(
      xn2, wfcT, (void*)hbuf, 4096, 4096, 1024, 1024, 0, nullptr, nullptr, nullptr);
  gemm256<4, true><<<dim3(256), dim3(512), 131072, stream>>>(
      hbuf, wprojT, (void*)P0, 4096, 1024, 4096, 1024, 64, P1, P2, P3);
  add5_kernel<<<dim3(4096), dim3(256), 0, stream>>>(P0, P1, P2, P3, x2, (float*)d_out);
}

// Round 22
// 237.628 us; speedup vs baseline: 1.0676x; 1.0126x over previous
//
#include <hip/hip_runtime.h>

#define EOT_ID 50256

typedef __attribute__((ext_vector_type(8))) short bf16x8;
typedef __attribute__((ext_vector_type(4))) float f32x4;
typedef __attribute__((ext_vector_type(16))) float f32x16;

#define GLOAD_LDS(g, l)                                                        \
  __builtin_amdgcn_global_load_lds(                                            \
      (const __attribute__((address_space(1))) unsigned int*)(g),              \
      (__attribute__((address_space(3))) unsigned int*)(l), 16, 0, 0)

__device__ __forceinline__ unsigned short f2bf(float f) {
  union { float f; unsigned int u; } v; v.f = f;
  unsigned int r = v.u + 0x7FFFu + ((v.u >> 16) & 1u);
  return (unsigned short)(r >> 16);
}
__device__ __forceinline__ float bf2f(unsigned short b) {
  union { unsigned int u; float f; } v; v.u = ((unsigned int)b) << 16;
  return v.f;
}
__device__ __forceinline__ unsigned int cvtpk(float lo, float hi) {
  unsigned int r;
  asm("v_cvt_pk_bf16_f32 %0, %1, %2" : "=v"(r) : "v"(lo), "v"(hi));
  return r;
}
__device__ __forceinline__ void plswap(unsigned int& a, unsigned int& b) {
  asm volatile("v_permlane32_swap_b32 %0, %1" : "+v"(a), "+v"(b));
}
union U8 { unsigned int u[4]; bf16x8 v; };

// ---------------- prep: RoPE tables (blocks 0..255) + doc-scan (block 256) ----
__global__ __launch_bounds__(256)
void prep_kernel(float* __restrict__ ct, float* __restrict__ st,
                 const int* __restrict__ ids, int* __restrict__ qstart) {
  if (blockIdx.x < 256) {
    const int idx = blockIdx.x * 256 + threadIdx.x;   // 65536
    const int s = idx >> 5, i = idx & 31;
    const float ang = (float)s * exp2f(-10.0f * (float)i / 31.0f);
    float sv, cv;
    sincosf(ang, &sv, &cv);
    ct[idx] = cv;
    st[idx] = sv;
  } else {
    __shared__ int a[2048], b2[2048];
    const int t = threadIdx.x;
    for (int i = t; i < 2048; i += 256)
      a[i] = (ids[i] == EOT_ID) ? i : 0;
    __syncthreads();
    int* cur = a; int* nxt = b2;
    for (int off = 1; off < 2048; off <<= 1) {
      for (int i = t; i < 2048; i += 256) {
        int v = cur[i];
        if (i >= off) { int u = cur[i - off]; v = (u > v) ? u : v; }
        nxt[i] = v;
      }
      __syncthreads();
      int* tmp = cur; cur = nxt; nxt = tmp;
    }
    for (int i = t; i < 2048; i += 256) qstart[i] = cur[i];
  }
}

// ---------------- merged weight transpose f32 [K][N] -> bf16 [N][K] ----------------
__global__ __launch_bounds__(256)
void wtrans4_kernel(const float* __restrict__ wqkv, const float* __restrict__ wo,
                    const float* __restrict__ wfc, const float* __restrict__ wproj,
                    unsigned short* __restrict__ wqkvT, unsigned short* __restrict__ woT,
                    unsigned short* __restrict__ wfcT, unsigned short* __restrict__ wprojT) {
  int blk = blockIdx.x;
  const float* in;
  unsigned short* out;
  int K, N;
  if (blk < 3072)      { in = wqkv;  out = wqkvT;  K = 1024; N = 3072; }
  else if (blk < 4096) { blk -= 3072; in = wo;    out = woT;    K = 1024; N = 1024; }
  else if (blk < 8192) { blk -= 4096; in = wfc;   out = wfcT;   K = 1024; N = 4096; }
  else                 { blk -= 8192; in = wproj; out = wprojT; K = 4096; N = 1024; }
  __shared__ float tile[32][33];
  const int nb = N >> 5;
  const int k0 = (blk / nb) << 5, n0 = (blk % nb) << 5;
  const int tx = threadIdx.x & 31, ty = threadIdx.x >> 5;
#pragma unroll
  for (int p = 0; p < 4; p++)
    tile[ty + p * 8][tx] = in[(size_t)(k0 + ty + p * 8) * N + n0 + tx];
  __syncthreads();
#pragma unroll
  for (int p = 0; p < 4; p++)
    out[(size_t)(n0 + ty + p * 8) * K + k0 + tx] = f2bf(tile[tx][ty + p * 8]);
}

// ---------------- K-split reduce: out = bf16(p0+p1+p2+p3) + f32 res ----------------
__global__ __launch_bounds__(256)
void add5_kernel(const unsigned short* __restrict__ p0,
                 const unsigned short* __restrict__ p1,
                 const unsigned short* __restrict__ p2,
                 const unsigned short* __restrict__ p3,
                 const float* __restrict__ res, float* __restrict__ out) {
  const int i = (blockIdx.x * 256 + threadIdx.x) * 4;
  const ushort4 a = *(const ushort4*)(p0 + i);
  const ushort4 b = *(const ushort4*)(p1 + i);
  const ushort4 c = *(const ushort4*)(p2 + i);
  const ushort4 d = *(const ushort4*)(p3 + i);
  float4 e = *(const float4*)(res + i);
  e.x += bf2f(a.x) + bf2f(b.x) + bf2f(c.x) + bf2f(d.x);
  e.y += bf2f(a.y) + bf2f(b.y) + bf2f(c.y) + bf2f(d.y);
  e.z += bf2f(a.z) + bf2f(b.z) + bf2f(c.z) + bf2f(d.z);
  e.w += bf2f(a.w) + bf2f(b.w) + bf2f(c.w) + bf2f(d.w);
  *(float4*)(out + i) = e;
}

// ---------------- LayerNorm (optional residual mix) ----------------
template<bool MIX>
__global__ __launch_bounds__(256)
void ln_kernel(const float* __restrict__ x, const float* __restrict__ x0,
               const float* __restrict__ lam, const float* __restrict__ w,
               float* __restrict__ xm, unsigned short* __restrict__ xn) {
  __shared__ float red[8];
  const int row = blockIdx.x, t = threadIdx.x;
  const size_t base = (size_t)row << 10;
  float4 v = *(const float4*)(x + base + t * 4);
  if (MIX) {
    const float l0 = lam[0], l1 = lam[1];
    const float4 v0 = *(const float4*)(x0 + base + t * 4);
    v.x = l0 * v.x + l1 * v0.x;
    v.y = l0 * v.y + l1 * v0.y;
    v.z = l0 * v.z + l1 * v0.z;
    v.w = l0 * v.w + l1 * v0.w;
    *(float4*)(xm + base + t * 4) = v;
  }
  float s = v.x + v.y + v.z + v.w;
  float q = v.x * v.x + v.y * v.y + v.z * v.z + v.w * v.w;
#pragma unroll
  for (int off = 1; off < 64; off <<= 1) {
    s += __shfl_xor(s, off);
    q += __shfl_xor(q, off);
  }
  const int wid = t >> 6;
  if ((t & 63) == 0) { red[wid] = s; red[4 + wid] = q; }
  __syncthreads();
  s = red[0] + red[1] + red[2] + red[3];
  q = red[4] + red[5] + red[6] + red[7];
  const float mu = s * (1.0f / 1024.0f);
  const float var = q * (1.0f / 1024.0f) - mu * mu;
  const float rstd = rsqrtf(var + 1e-6f);
  const float4 wv = *(const float4*)(w + t * 4);
  ushort4 u;
  u.x = f2bf((v.x - mu) * rstd * wv.x);
  u.y = f2bf((v.y - mu) * rstd * wv.y);
  u.z = f2bf((v.z - mu) * rstd * wv.z);
  u.w = f2bf((v.w - mu) * rstd * wv.w);
  *(ushort4*)(xn + base + t * 4) = u;
}

// ---------------- GEMM (128-tile, 2-phase): used for wo ----------------
template<int EPI, int BM, int BK>
__global__ __launch_bounds__(256, 4)
void gemm_bt(const unsigned short* __restrict__ A,
             const unsigned short* __restrict__ Bt,
             void* __restrict__ Cout,
             const float* __restrict__ res,
             int M, int N, int K) {
  __shared__ unsigned short As[2][BM * BK];
  __shared__ unsigned short Bs[2][128 * BK];
  const int t = threadIdx.x;
  const int wid = t >> 6;
  const int lane = t & 63;
  const int ln = lane & 15, kg = lane >> 4;
  const int nbm = M / BM;
  const int xcd = (int)blockIdx.x & 7, rr = (int)blockIdx.x >> 3;
  const int slab = nbm >> 3;
  const int bm = xcd * slab + (rr % slab);
  const int bn = rr / slab;
  const int m0 = bm * BM, n0 = bn << 7;
  const int wrow = (BM == 128) ? ((wid >> 1) * 64) : 0;
  const int wcol = (BM == 128) ? ((wid & 1) * 64) : (wid * 32);
  constexpr int NJ = (BM == 128) ? 4 : 2;
  constexpr int LA = BM * BK / 2048;
  constexpr int LB = 128 * BK / 2048;
  constexpr int KC = BK / 32;

  f32x4 acc[4][NJ] = {};

  const unsigned short* Abase = A + (size_t)m0 * K;
  const unsigned short* Bbase = Bt + (size_t)n0 * K;

  auto swz = [&](int row, int chunk) -> int {
    if constexpr (BK == 32) return chunk ^ ((row >> 1) & 3);
    else                    return chunk ^ (row & 7);
  };

  auto STAGE = [&](int bb, int kt) {
#pragma unroll
    for (int p = 0; p < LA; p++) {
      const int e = t * 8 + p * 2048;
      const int r = e / BK;
      const int cs = swz(r, (e >> 3) & (BK / 8 - 1));
      GLOAD_LDS(Abase + (size_t)r * K + kt + cs * 8, &As[bb][p * 2048 + wid * 512]);
    }
#pragma unroll
    for (int p = 0; p < LB; p++) {
      const int e = t * 8 + p * 2048;
      const int r = e / BK;
      const int cs = swz(r, (e >> 3) & (BK / 8 - 1));
      GLOAD_LDS(Bbase + (size_t)r * K + kt + cs * 8, &Bs[bb][p * 2048 + wid * 512]);
    }
  };

  STAGE(0, 0);
  int cur = 0;
  const int nk = K / BK;
  for (int ki = 0; ki < nk; ki++) {
    if (ki + 1 < nk) {
      STAGE(cur ^ 1, (ki + 1) * BK);
      if constexpr (LA + LB == 4)
        asm volatile("s_waitcnt vmcnt(4)" ::: "memory");
      else
        asm volatile("s_waitcnt vmcnt(6)" ::: "memory");
    } else {
      asm volatile("s_waitcnt vmcnt(0)" ::: "memory");
    }
    __builtin_amdgcn_s_barrier();

#pragma unroll
    for (int c = 0; c < KC; c++) {
      bf16x8 af[4], bfr[NJ];
#pragma unroll
      for (int i = 0; i < 4; i++) {
        const int ra = wrow + i * 16 + ln;
        af[i] = *(const bf16x8*)(&As[cur][ra * BK + swz(ra, c * 4 + kg) * 8]);
      }
#pragma unroll
      for (int j = 0; j < NJ; j++) {
        const int rb = wcol + j * 16 + ln;
        bfr[j] = *(const bf16x8*)(&Bs[cur][rb * BK + swz(rb, c * 4 + kg) * 8]);
      }
#pragma unroll
      for (int i = 0; i < 4; i++)
#pragma unroll
        for (int j = 0; j < NJ; j++)
          acc[i][j] = __builtin_amdgcn_mfma_f32_16x16x32_bf16(af[i], bfr[j], acc[i][j], 0, 0, 0);
    }

    __builtin_amdgcn_s_barrier();
    cur ^= 1;
  }

#pragma unroll
  for (int i = 0; i < 4; i++) {
#pragma unroll
    for (int j = 0; j < NJ; j++) {
#pragma unroll
      for (int r = 0; r < 4; r++) {
        const int row = m0 + wrow + i * 16 + kg * 4 + r;
        const int col = n0 + wcol + j * 16 + ln;
        const size_t idx = (size_t)row * N + col;
        float v = acc[i][j][r];
        if (EPI == 0) {
          ((float*)Cout)[idx] = v;
        } else if (EPI == 1) {
          ((float*)Cout)[idx] = v + res[idx];
        } else if (EPI == 2) {
          v = fmaxf(v, 0.0f);
          ((unsigned short*)Cout)[idx] = f2bf(v * v);
        } else {
          ((unsigned short*)Cout)[idx] = f2bf(v);
        }
      }
    }
  }
}

// ---------------- GEMM 256x256 8-phase (T2+T3+T4+T5): qkv, fc, proj(K-split) ----
#define SWZ9(x) ((x) ^ ((((x) >> 9) & 1) << 5))

#define RD_A(BUF, QM)                                                          \
  {                                                                            \
    const char* sb_ = smem + (((BUF)*2 + 0) * 2 + (QM)) * 16384;               \
    _Pragma("unroll") for (int i_ = 0; i_ < 4; i_++)                           \
    _Pragma("unroll") for (int kc_ = 0; kc_ < 2; kc_++) {                      \
      int x_ = kc_ * 8192 + (wr * 64 + i_ * 16 + ln) * 64 + kg * 16;           \
      Af[i_][kc_] = *(const bf16x8*)(sb_ + SWZ9(x_));                          \
    }                                                                          \
  }

#define RD_B(BUF, QN, BARR)                                                    \
  {                                                                            \
    const char* sb_ = smem + (((BUF)*2 + 1) * 2 + (QN)) * 16384;               \
    _Pragma("unroll") for (int j_ = 0; j_ < 2; j_++)                           \
    _Pragma("unroll") for (int kc_ = 0; kc_ < 2; kc_++) {                      \
      int x_ = kc_ * 8192 + (wc * 32 + j_ * 16 + ln) * 64 + kg * 16;           \
      BARR[j_][kc_] = *(const bf16x8*)(sb_ + SWZ9(x_));                        \
    }                                                                          \
  }

#define MFMAQ(QM, QN, BARR)                                                    \
  _Pragma("unroll") for (int i_ = 0; i_ < 4; i_++)                             \
  _Pragma("unroll") for (int j_ = 0; j_ < 2; j_++)                             \
  _Pragma("unroll") for (int kc_ = 0; kc_ < 2; kc_++)                          \
    acc[QM][QN][i_][j_] = __builtin_amdgcn_mfma_f32_16x16x32_bf16(             \
        Af[i_][kc_], BARR[j_][kc_], acc[QM][QN][i_][j_], 0, 0, 0);

#define PHTAIL()                                                               \
  __builtin_amdgcn_s_barrier();                                                \
  asm volatile("s_waitcnt lgkmcnt(0)" ::: "memory");                           \
  __builtin_amdgcn_sched_barrier(0);                                           \
  __builtin_amdgcn_s_setprio(1)

#define PHEND()                                                                \
  __builtin_amdgcn_s_setprio(0);                                               \
  __builtin_amdgcn_s_barrier()

template<int EPI, bool KSPLIT4>
__global__ __launch_bounds__(512, 2)
void gemm256(const unsigned short* __restrict__ A,
             const unsigned short* __restrict__ Bt,
             void* __restrict__ Cout,
             int M, int N, int Kfull, int Klen, int nInner,
             unsigned short* __restrict__ o1, unsigned short* __restrict__ o2,
             unsigned short* __restrict__ o3) {
  extern __shared__ char smem[];
  const int tid = threadIdx.x;
  const int wid = tid >> 6, lane = tid & 63;
  const int wr = wid >> 2, wc = wid & 3;
  const int ln = lane & 15, kg = lane >> 4;
  int blkid = (int)blockIdx.x;
  int split = 0;
  if constexpr (KSPLIT4) {
    split = blkid / nInner;
    blkid -= split * nInner;
  }
  const int nbm = M >> 8;
  const int xcd = blkid & 7, rr = blkid >> 3;
  const int slab = nbm >> 3;
  const int bm = xcd * slab + (rr % slab);
  const int bn = rr / slab;
  const int m0 = bm << 8, n0 = bn << 8;
  const size_t K2 = (size_t)Kfull * 2;
  const size_t kb0 = (size_t)split * Klen * 2;
  const char* Ac = (const char*)A;
  const char* Bc = (const char*)Bt;

  f32x4 acc[2][2][4][2] = {};
  bf16x8 Af[4][2], B0[2][2], B1[2][2];

  auto STG = [&](int buf, int ab, int h, int tile) {
    const char* gb = ab ? Bc : Ac;
    const int ro = (ab ? n0 : m0) + h * 128;
    char* db = smem + ((buf * 2 + ab) * 2 + h) * 16384;
#pragma unroll
    for (int q = 0; q < 2; q++) {
      const int p0 = q * 8192 + tid * 16;
      const int lin = SWZ9(p0);
      GLOAD_LDS(gb + (size_t)(ro + ((lin >> 6) & 127)) * K2 + kb0 +
                    (size_t)tile * 128 + (lin >> 13) * 64 + (lin & 63),
                db + p0);
    }
  };

  STG(0, 0, 0, 0); STG(0, 0, 1, 0); STG(0, 1, 0, 0); STG(0, 1, 1, 0);
  STG(1, 0, 0, 1); STG(1, 1, 0, 1); STG(1, 1, 1, 1);
  asm volatile("s_waitcnt vmcnt(6)" ::: "memory");
  __builtin_amdgcn_s_barrier();

  const int niter = Klen >> 7;   // pairs of 64-wide K-tiles
  for (int it = 0; it < niter; it++) {
    const int tA = 2 * it, tB = tA + 1;
    const bool more = (it + 1 < niter);

    RD_A(0, 0); RD_B(0, 0, B0);
    STG(1, 0, 1, tB);
    PHTAIL(); MFMAQ(0, 0, B0); PHEND();
    RD_B(0, 1, B1);
    if (more) STG(0, 0, 0, tA + 2);
    PHTAIL(); MFMAQ(0, 1, B1); PHEND();
    RD_A(0, 1);
    if (more) STG(0, 1, 0, tA + 2);
    PHTAIL(); MFMAQ(1, 0, B0); PHEND();
    if (more) {
      STG(0, 1, 1, tA + 2);
      asm volatile("s_waitcnt vmcnt(6)" ::: "memory");
    } else {
      asm volatile("s_waitcnt vmcnt(0)" ::: "memory");
    }
    PHTAIL(); MFMAQ(1, 1, B1); PHEND();
    RD_A(1, 0); RD_B(1, 0, B0);
    if (more) STG(0, 0, 1, tA + 2);
    PHTAIL(); MFMAQ(0, 0, B0); PHEND();
    RD_B(1, 1, B1);
    if (more) STG(1, 0, 0, tB + 2);
    PHTAIL(); MFMAQ(0, 1, B1); PHEND();
    RD_A(1, 1);
    if (more) STG(1, 1, 0, tB + 2);
    PHTAIL(); MFMAQ(1, 0, B0); PHEND();
    if (more) {
      STG(1, 1, 1, tB + 2);
      asm volatile("s_waitcnt vmcnt(6)" ::: "memory");
    }
    PHTAIL(); MFMAQ(1, 1, B1); PHEND();
  }

  unsigned short* bout = (unsigned short*)Cout;
  if constexpr (KSPLIT4) {
    if (split == 1) bout = o1;
    else if (split == 2) bout = o2;
    else if (split == 3) bout = o3;
  }

#pragma unroll
  for (int qm = 0; qm < 2; qm++)
#pragma unroll
    for (int qn = 0; qn < 2; qn++)
#pragma unroll
      for (int i = 0; i < 4; i++)
#pragma unroll
        for (int j = 0; j < 2; j++)
#pragma unroll
          for (int r = 0; r < 4; r++) {
            const int row = m0 + qm * 128 + wr * 64 + i * 16 + kg * 4 + r;
            const int col = n0 + qn * 128 + wc * 32 + j * 16 + ln;
            const size_t idx = (size_t)row * N + col;
            float v = acc[qm][qn][i][j][r];
            if (EPI == 2) {
              v = fmaxf(v, 0.0f);
              ((unsigned short*)Cout)[idx] = f2bf(v * v);
            } else if (EPI == 3) {
              ((unsigned short*)Cout)[idx] = f2bf(v);
            } else {
              bout[idx] = f2bf(v);      // bf16 K-split partial
            }
          }
}

// ---------------- RoPE + RMSNorm + v-mix (qkv in bf16) ----------------
__global__ __launch_bounds__(256)
void rope_rms_kernel(const unsigned short* __restrict__ qkv,
                     const float* __restrict__ ct, const float* __restrict__ st,
                     const float* __restrict__ ve, const float* __restrict__ salam,
                     unsigned short* __restrict__ Qh, unsigned short* __restrict__ Kh,
                     unsigned short* __restrict__ Vt) {
  const int t = threadIdx.x;
  const int wid = t >> 6, i = t & 63;
  const int g = blockIdx.x * 4 + wid;      // (b,s,h)
  const int b = g >> 14;
  const int s = (g >> 3) & 2047;
  const int h = g & 7;
  const unsigned short* base = qkv + (size_t)(b * 2048 + s) * 3072 + h * 128;
  float c = 1.0f, sn = 0.0f;
  if (i < 32) { c = ct[s * 32 + i]; sn = st[s * 32 + i]; }
  const float q1 = bf2f(base[i]), q2 = bf2f(base[64 + i]);
  const float k1 = bf2f(base[1024 + i]), k2 = bf2f(base[1024 + 64 + i]);
  const float q1r = q1 * c + q2 * sn, q2r = q2 * c - q1 * sn;
  const float k1r = k1 * c + k2 * sn, k2r = k2 * c - k1 * sn;
  float sq = q1r * q1r + q2r * q2r;
  float sk = k1r * k1r + k2r * k2r;
#pragma unroll
  for (int off = 1; off < 64; off <<= 1) {
    sq += __shfl_xor(sq, off);
    sk += __shfl_xor(sk, off);
  }
  const float eps = 1.1920929e-7f;
  const float rq = rsqrtf(sq * (1.0f / 128.0f) + eps);
  const float rk = rsqrtf(sk * (1.0f / 128.0f) + eps);
  unsigned short* qp = Qh + (((size_t)(b * 2048 + s) * 8 + h) << 7);
  unsigned short* kp = Kh + (((size_t)(b * 2048 + s) * 8 + h) << 7);
  qp[i] = f2bf(q1r * rq); qp[64 + i] = f2bf(q2r * rq);
  kp[i] = f2bf(k1r * rk); kp[64 + i] = f2bf(k2r * rk);
  const float l0 = salam[0], l1 = salam[1];
  const float* vep = ve + (size_t)s * 1024 + h * 128;
  const float v1 = l0 * bf2f(base[2048 + i]) + l1 * vep[i];
  const float v2 = l0 * bf2f(base[2048 + 64 + i]) + l1 * vep[64 + i];
  unsigned short* vp = Vt + (((size_t)(b * 8 + h) * 128) << 11) + s;
  vp[(size_t)i << 11] = f2bf(v1);
  vp[(size_t)(64 + i) << 11] = f2bf(v2);
}

// ---------------- flash attention, doc-causal (fixed-shift softmax) ----------------
// Scores are provably bounded: RMSNorm gives ||q||^2 = ||k||^2 = 128, so
// |s*SC| <= 128*0.12*log2e ~= 22.16. Fixed shift M=23 => p = exp2(s*SC - M)
// in (0,1], l >= exp2(22.16-23) ~= 0.57 (diagonal always present). Deletes
// all online-max tracking/rescale and the merge's m-exchange (plain sums).
__global__ __launch_bounds__(512, 2)
void attn_kernel(const unsigned short* __restrict__ Qh,
                 const unsigned short* __restrict__ Kh,
                 const unsigned short* __restrict__ Vt,
                 const int* __restrict__ qstart,
                 unsigned short* __restrict__ Out) {
  extern __shared__ char asmem[];   // 128KB: K [4 kw][2 buf][8KB] @0; V same @65536

  const int blk = blockIdx.x;        // 256 blocks
  const int pid = blk >> 4;          // 0..15
  const int bh = blk & 15;
  const int b = bh >> 3, h = bh & 7;
  const int t = threadIdx.x;
  const int wid = t >> 6, lane = t & 63;
  const int qw = wid & 1, kw = wid >> 1;    // kw 0..3
  const int ln5 = lane & 31, hi = lane >> 5;
  const int tp = qw * 64 + lane;            // staging tid within kw-group
  const float SC = 0.12f * 1.4426950408889634f;
  const float MM = 23.0f;                   // fixed softmax shift (>= max |s*SC|)

  char* Kb = asmem + kw * 16384;
  char* Vb = asmem + 65536 + kw * 16384;

  const char* ksrc[4];
  const char* vsrc[4];
  char* kdst[4];
  char* vdst[4];
#pragma unroll
  for (int r = 0; r < 4; r++) {
    {
      const int e = tp * 16 + r * 2048;
      const int row = e >> 8;
      const int ch = (e >> 4) & 15;
      const int sch = ch ^ ((row ^ (row >> 3)) & 7);
      ksrc[r] = (const char*)(Kh + (((size_t)(b * 2048 + row) * 8 + h) << 7) + sch * 8);
      kdst[r] = Kb + r * 2048 + qw * 1024 + (lane << 4);
    }
    {
      const int e = tp * 16 + r * 2048;
      const int row = e >> 6;
      const int ch = (e >> 4) & 3;
      const int sch = ch ^ ((row >> 1) & 3);
      vsrc[r] = (const char*)(Vt + (((size_t)((b * 8 + h) * 128 + row)) << 11) + sch * 8);
      vdst[r] = Vb + r * 2048 + qw * 1024 + (lane << 4);
    }
  }

  auto STAGE = [&](int bb, int kt) {
    const size_t kof = (size_t)kt * 2048;
    const size_t vof = (size_t)kt * 2;
#pragma unroll
    for (int r = 0; r < 4; r++)
      GLOAD_LDS(ksrc[r] + kof, kdst[r] + bb * 8192);
#pragma unroll
    for (int r = 0; r < 4; r++)
      GLOAD_LDS(vsrc[r] + vof, vdst[r] + bb * 8192);
  };

  for (int ph = 0; ph < 2; ph++) {
    const int qt = ph ? (31 - pid) : pid;
    const int q0 = qt << 6;
    const int qrow = q0 + qw * 32;

    bf16x8 qf[8];
    {
      const unsigned short* qp =
          Qh + (((size_t)(b * 2048 + qrow + ln5) * 8 + h) << 7) + hi * 8;
#pragma unroll
      for (int c = 0; c < 8; c++) qf[c] = *(const bf16x8*)(qp + c * 16);
    }
    const int qid = qrow + ln5;
    const int qs = qstart[qid];
    int qsmax = qs;
#pragma unroll
    for (int off = 1; off < 32; off <<= 1)
      qsmax = max(qsmax, __shfl_xor(qsmax, off));

    float l = 0.0f;
    f32x16 o[4] = {};

    const int kt0 = qstart[q0] & ~31;
    const int T = (q0 + 64 - kt0) >> 5;

    __syncthreads();
    STAGE(0, kt0 + kw * 32);
    int cur = 0;
    const int nLoop = (T + 3) >> 2;

    for (int i = 0; i < nLoop; i++) {
      const int tid2 = 4 * i + kw;
      const bool hasnext = (tid2 + 4) < T;
      if (hasnext) {
        STAGE(cur ^ 1, kt0 + (tid2 + 4) * 32);
        asm volatile("s_waitcnt vmcnt(8)" ::: "memory");
      } else {
        asm volatile("s_waitcnt vmcnt(0)" ::: "memory");
      }
      __builtin_amdgcn_s_barrier();

      if (tid2 < T) {
        const int kt = kt0 + tid2 * 32;
        const unsigned short* ksb = (const unsigned short*)(Kb + cur * 8192);
        const unsigned short* vsb = (const unsigned short*)(Vb + cur * 8192);

        f32x16 sacc = {};
        {
          const int key = ln5;
          const int kx = (key ^ (key >> 3)) & 7;
          const unsigned short* krow = &ksb[key * 128];
          __builtin_amdgcn_s_setprio(1);
#pragma unroll
          for (int c = 0; c < 8; c++) {
            bf16x8 kf = *(const bf16x8*)(krow + (((2 * c + hi) ^ kx) << 3));
            sacc = __builtin_amdgcn_mfma_f32_32x32x16_bf16(kf, qf[c], sacc, 0, 0, 0);
          }
          __builtin_amdgcn_s_setprio(0);
        }

        const bool full = (kt + 32 <= qrow) && (kt >= qsmax);

        float p[16];
        if (full) {
#pragma unroll
          for (int i2 = 0; i2 < 16; i2++)
            p[i2] = exp2f(sacc[i2] * SC - MM);
        } else {
#pragma unroll
          for (int i2 = 0; i2 < 16; i2++) {
            const int key = kt + (i2 & 3) + 8 * (i2 >> 2) + 4 * hi;
            const bool valid = (key <= qid) && (key >= qs);
            const float ts = valid ? sacc[i2] * SC : -1e30f;
            p[i2] = exp2f(ts - MM);           // masked underflows to 0
          }
        }
        // pairwise sum tree (depth 4)
        float t0 = p[0] + p[1], t1 = p[2] + p[3], t2 = p[4] + p[5], t3 = p[6] + p[7];
        float t4 = p[8] + p[9], t5 = p[10] + p[11], t6 = p[12] + p[13], t7 = p[14] + p[15];
        t0 += t1; t2 += t3; t4 += t5; t6 += t7;
        t0 += t2; t4 += t6;
        float sum = t0 + t4;
        sum += __shfl_xor(sum, 32);
        l += sum;

        bf16x8 pa[2];
#pragma unroll
        for (int bb2 = 0; bb2 < 2; bb2++) {
          unsigned int a0 = cvtpk(p[bb2 * 8 + 0], p[bb2 * 8 + 1]);
          unsigned int b0 = cvtpk(p[bb2 * 8 + 4], p[bb2 * 8 + 5]);
          unsigned int a1 = cvtpk(p[bb2 * 8 + 2], p[bb2 * 8 + 3]);
          unsigned int b1 = cvtpk(p[bb2 * 8 + 6], p[bb2 * 8 + 7]);
          plswap(a0, b0);
          plswap(a1, b1);
          U8 u; u.u[0] = a0; u.u[1] = a1; u.u[2] = b0; u.u[3] = b1;
          pa[bb2] = u.v;
        }

        __builtin_amdgcn_s_setprio(1);
#pragma unroll
        for (int dt = 0; dt < 4; dt++) {
          const int d = dt * 32 + ln5;
          const int dx = (d >> 1) & 3;
          const unsigned short* vrow = &vsb[d * 32];
#pragma unroll
          for (int ks = 0; ks < 2; ks++) {
            bf16x8 vf = *(const bf16x8*)(vrow + (((2 * ks + hi) ^ dx) << 3));
            o[dt] = __builtin_amdgcn_mfma_f32_32x32x16_bf16(pa[ks], vf, o[dt], 0, 0, 0);
          }
        }
        __builtin_amdgcn_s_setprio(0);
      }

      __builtin_amdgcn_s_barrier();
      cur ^= 1;
    }

    // ---- 4-way merge through (now idle) LDS: plain sums (shared fixed M) ----
    __syncthreads();
    float* oex = (float*)asmem;                 // [3][2 qw][64 lanes][65]
    float* llx = (float*)(asmem + 99840);       // [3][2][32]
    if (kw != 0) {
      if (lane < 32)
        llx[((kw - 1) * 2 + qw) * 32 + lane] = l;
      float* dst = oex + (((kw - 1) * 2 + qw) * 64 + lane) * 65;
#pragma unroll
      for (int dt = 0; dt < 4; dt++)
#pragma unroll
        for (int r = 0; r < 16; r++) dst[dt * 16 + r] = o[dt][r];
    }
    __syncthreads();
    if (kw == 0) {
      const float l1 = llx[(0 * 2 + qw) * 32 + ln5];
      const float l2 = llx[(1 * 2 + qw) * 32 + ln5];
      const float l3 = llx[(2 * 2 + qw) * 32 + ln5];
      const float inv = 1.0f / (l + l1 + l2 + l3);
      const float* s1 = oex + ((0 * 2 + qw) * 64 + lane) * 65;
      const float* s2 = oex + ((1 * 2 + qw) * 64 + lane) * 65;
      const float* s3 = oex + ((2 * 2 + qw) * 64 + lane) * 65;
#pragma unroll
      for (int r = 0; r < 16; r++) {
        const int crow = (r & 3) + 8 * (r >> 2) + 4 * hi;
        const float ivr = __shfl(inv, crow);
        const int q = qrow + crow;
        unsigned short* op = Out + (((size_t)(b * 2048 + q)) << 10) + h * 128 + ln5;
#pragma unroll
        for (int dt = 0; dt < 4; dt++)
          op[dt * 32] = f2bf((o[dt][r] + s1[dt * 16 + r] +
                              s2[dt * 16 + r] + s3[dt * 16 + r]) * ivr);
      }
    }
  }
}

// ---------------- launcher ----------------
extern "C" void kernel_launch(void* const* d_in, const int* in_sizes, int n_in,
                              void* d_out, int out_size, void* d_ws, size_t ws_size,
                              hipStream_t stream) {
  const float* x     = (const float*)d_in[0];
  const float* vemb  = (const float*)d_in[1];
  const float* x0    = (const float*)d_in[2];
  const float* lam   = (const float*)d_in[3];
  const float* slam  = (const float*)d_in[4];
  const float* ln1w  = (const float*)d_in[5];
  const float* ln2w  = (const float*)d_in[6];
  const float* wqkv  = (const float*)d_in[7];
  const float* wo    = (const float*)d_in[8];
  const float* wfc   = (const float*)d_in[9];
  const float* wproj = (const float*)d_in[10];
  const int*   ids   = (const int*)d_in[11];

  char* ws = (char*)d_ws;
  unsigned short* wqkvT  = (unsigned short*)(ws + 0);          //  6 MB
  unsigned short* woT    = (unsigned short*)(ws + 6291456);    //  2 MB
  unsigned short* wfcT   = (unsigned short*)(ws + 8388608);    //  8 MB
  unsigned short* wprojT = (unsigned short*)(ws + 16777216);   //  8 MB
  float*          xm     = (float*)(ws + 25165824);            // 16 MB
  unsigned short* qkv    = (unsigned short*)(ws + 41943040);   // 24 MB (bf16)
  unsigned short* hbuf   = (unsigned short*)(ws + 41943040);   // reuse (32 MB)
  unsigned short* xn1    = (unsigned short*)(ws + 92274688);   //  8 MB
  unsigned short* ao     = (unsigned short*)(ws + 92274688);   // reuse
  unsigned short* qh     = (unsigned short*)(ws + 100663296);  //  8 MB
  unsigned short* xn2    = (unsigned short*)(ws + 100663296);  // reuse
  unsigned short* kh     = (unsigned short*)(ws + 109051904);  //  8 MB
  unsigned short* vt     = (unsigned short*)(ws + 117440512);  //  8 MB
  float*          x2     = (float*)(ws + 109051904);           // reuse kh+vt (16 MB)
  float*          ctab   = (float*)(ws + 125829120);
  float*          stab   = (float*)(ws + 126091264);
  int*            qstart = (int*)(ws + 126353408);
  // bf16 K-split partials (8 MB each, all regions dead at proj time):
  unsigned short* P0 = (unsigned short*)(ws + 0);          // wqkvT+woT
  unsigned short* P1 = (unsigned short*)(ws + 8388608);    // wfcT (dead after fc)
  unsigned short* P2 = (unsigned short*)(ws + 25165824);   // xm lower half (dead after wo)
  unsigned short* P3 = (unsigned short*)(ws + 33554432);   // xm upper half

  static int attr_done = 0;
  if (!attr_done) {
    hipFuncSetAttribute((const void*)gemm256<3, false>,
                        hipFuncAttributeMaxDynamicSharedMemorySize, 131072);
    hipFuncSetAttribute((const void*)gemm256<2, false>,
                        hipFuncAttributeMaxDynamicSharedMemorySize, 131072);
    hipFuncSetAttribute((const void*)gemm256<4, true>,
                        hipFuncAttributeMaxDynamicSharedMemorySize, 131072);
    hipFuncSetAttribute((const void*)attn_kernel,
                        hipFuncAttributeMaxDynamicSharedMemorySize, 131072);
    attr_done = 1;
  }

  prep_kernel<<<dim3(257), dim3(256), 0, stream>>>(ctab, stab, ids, qstart);
  wtrans4_kernel<<<dim3(12288), dim3(256), 0, stream>>>(wqkv, wo, wfc, wproj,
                                                        wqkvT, woT, wfcT, wprojT);

  ln_kernel<true><<<dim3(4096), dim3(256), 0, stream>>>(x, x0, lam, ln1w, xm, xn1);
  gemm256<3, false><<<dim3(192), dim3(512), 131072, stream>>>(
      xn1, wqkvT, (void*)qkv, 4096, 3072, 1024, 1024, 0, nullptr, nullptr, nullptr);
  rope_rms_kernel<<<dim3(8192), dim3(256), 0, stream>>>(qkv, ctab, stab, vemb, slam, qh, kh, vt);
  attn_kernel<<<dim3(256), dim3(512), 131072, stream>>>(qh, kh, vt, qstart, ao);
  gemm_bt<1, 64, 64><<<dim3(64 * 8), dim3(256), 0, stream>>>(ao, woT, (void*)x2, xm,
                                                             4096, 1024, 1024);
  ln_kernel<false><<<dim3(4096), dim3(256), 0, stream>>>(x2, (const float*)nullptr,
                                                         (const float*)nullptr, ln2w,
                                                         (float*)nullptr, xn2);
  gemm256<2, false><<<dim3(256), dim3(512), 131072, stream>>>(
      xn2, wfcT, (void*)hbuf, 4096, 4096, 1024, 1024, 0, nullptr, nullptr, nullptr);
  gemm256<4, true><<<dim3(256), dim3(512), 131072, stream>>>(
      hbuf, wprojT, (void*)P0, 4096, 1024, 4096, 1024, 64, P1, P2, P3);
  add5_kernel<<<dim3(4096), dim3(256), 0, stream>>>(P0, P1, P2, P3, x2, (float*)d_out);
}

// Round 23
// 233.072 us; speedup vs baseline: 1.0884x; 1.0195x over previous
//
#include <hip/hip_runtime.h>

#define EOT_ID 50256

typedef __attribute__((ext_vector_type(8))) short bf16x8;
typedef __attribute__((ext_vector_type(4))) float f32x4;
typedef __attribute__((ext_vector_type(16))) float f32x16;

#define GLOAD_LDS(g, l)                                                        \
  __builtin_amdgcn_global_load_lds(                                            \
      (const __attribute__((address_space(1))) unsigned int*)(g),              \
      (__attribute__((address_space(3))) unsigned int*)(l), 16, 0, 0)

__device__ __forceinline__ unsigned short f2bf(float f) {
  union { float f; unsigned int u; } v; v.f = f;
  unsigned int r = v.u + 0x7FFFu + ((v.u >> 16) & 1u);
  return (unsigned short)(r >> 16);
}
__device__ __forceinline__ float bf2f(unsigned short b) {
  union { unsigned int u; float f; } v; v.u = ((unsigned int)b) << 16;
  return v.f;
}
__device__ __forceinline__ unsigned int cvtpk(float lo, float hi) {
  unsigned int r;
  asm("v_cvt_pk_bf16_f32 %0, %1, %2" : "=v"(r) : "v"(lo), "v"(hi));
  return r;
}
__device__ __forceinline__ void plswap(unsigned int& a, unsigned int& b) {
  asm volatile("v_permlane32_swap_b32 %0, %1" : "+v"(a), "+v"(b));
}
union U8 { unsigned int u[4]; bf16x8 v; };

// ---------------- fused setup: wtrans4 [0,12288) + ln1 [12288,16384)
//                  + rope tables [16384,16640) + doc-scan [16640] ----------------
__global__ __launch_bounds__(256)
void setup_kernel(const float* __restrict__ wqkv, const float* __restrict__ wo,
                  const float* __restrict__ wfc, const float* __restrict__ wproj,
                  unsigned short* __restrict__ wqkvT, unsigned short* __restrict__ woT,
                  unsigned short* __restrict__ wfcT, unsigned short* __restrict__ wprojT,
                  const float* __restrict__ x, const float* __restrict__ x0,
                  const float* __restrict__ lam, const float* __restrict__ w1,
                  float* __restrict__ xm, unsigned short* __restrict__ xn,
                  float* __restrict__ ct, float* __restrict__ st,
                  const int* __restrict__ ids, int* __restrict__ qstart) {
  __shared__ float tile[32][33];
  __shared__ float red[8];
  __shared__ int a[2048], b2[2048];
  const int gblk = blockIdx.x;
  const int t = threadIdx.x;

  if (gblk < 12288) {
    // ---- weight transpose f32 [K][N] -> bf16 [N][K] ----
    int blk = gblk;
    const float* in;
    unsigned short* out;
    int K, N;
    if (blk < 3072)      { in = wqkv;  out = wqkvT;  K = 1024; N = 3072; }
    else if (blk < 4096) { blk -= 3072; in = wo;    out = woT;    K = 1024; N = 1024; }
    else if (blk < 8192) { blk -= 4096; in = wfc;   out = wfcT;   K = 1024; N = 4096; }
    else                 { blk -= 8192; in = wproj; out = wprojT; K = 4096; N = 1024; }
    const int nb = N >> 5;
    const int k0 = (blk / nb) << 5, n0 = (blk % nb) << 5;
    const int tx = t & 31, ty = t >> 5;
#pragma unroll
    for (int p = 0; p < 4; p++)
      tile[ty + p * 8][tx] = in[(size_t)(k0 + ty + p * 8) * N + n0 + tx];
    __syncthreads();
#pragma unroll
    for (int p = 0; p < 4; p++)
      out[(size_t)(n0 + ty + p * 8) * K + k0 + tx] = f2bf(tile[tx][ty + p * 8]);
  } else if (gblk < 16384) {
    // ---- ln1 with residual mix ----
    const int row = gblk - 12288;
    const size_t base = (size_t)row << 10;
    float4 v = *(const float4*)(x + base + t * 4);
    const float l0 = lam[0], l1 = lam[1];
    const float4 v0 = *(const float4*)(x0 + base + t * 4);
    v.x = l0 * v.x + l1 * v0.x;
    v.y = l0 * v.y + l1 * v0.y;
    v.z = l0 * v.z + l1 * v0.z;
    v.w = l0 * v.w + l1 * v0.w;
    *(float4*)(xm + base + t * 4) = v;
    float s = v.x + v.y + v.z + v.w;
    float q = v.x * v.x + v.y * v.y + v.z * v.z + v.w * v.w;
#pragma unroll
    for (int off = 1; off < 64; off <<= 1) {
      s += __shfl_xor(s, off);
      q += __shfl_xor(q, off);
    }
    const int wid = t >> 6;
    if ((t & 63) == 0) { red[wid] = s; red[4 + wid] = q; }
    __syncthreads();
    s = red[0] + red[1] + red[2] + red[3];
    q = red[4] + red[5] + red[6] + red[7];
    const float mu = s * (1.0f / 1024.0f);
    const float var = q * (1.0f / 1024.0f) - mu * mu;
    const float rstd = rsqrtf(var + 1e-6f);
    const float4 wv = *(const float4*)(w1 + t * 4);
    ushort4 u;
    u.x = f2bf((v.x - mu) * rstd * wv.x);
    u.y = f2bf((v.y - mu) * rstd * wv.y);
    u.z = f2bf((v.z - mu) * rstd * wv.z);
    u.w = f2bf((v.w - mu) * rstd * wv.w);
    *(ushort4*)(xn + base + t * 4) = u;
  } else if (gblk < 16640) {
    // ---- RoPE tables ----
    const int idx = (gblk - 16384) * 256 + t;   // 65536
    const int s = idx >> 5, i = idx & 31;
    const float ang = (float)s * exp2f(-10.0f * (float)i / 31.0f);
    float sv, cv;
    sincosf(ang, &sv, &cv);
    ct[idx] = cv;
    st[idx] = sv;
  } else {
    // ---- doc-start max-scan ----
    for (int i = t; i < 2048; i += 256)
      a[i] = (ids[i] == EOT_ID) ? i : 0;
    __syncthreads();
    int* cur = a; int* nxt = b2;
    for (int off = 1; off < 2048; off <<= 1) {
      for (int i = t; i < 2048; i += 256) {
        int v = cur[i];
        if (i >= off) { int u = cur[i - off]; v = (u > v) ? u : v; }
        nxt[i] = v;
      }
      __syncthreads();
      int* tmp = cur; cur = nxt; nxt = tmp;
    }
    for (int i = t; i < 2048; i += 256) qstart[i] = cur[i];
  }
}

// ---------------- K-split reduce: out = bf16(p0+p1+p2+p3) + f32 res ----------------
__global__ __launch_bounds__(256)
void add5_kernel(const unsigned short* __restrict__ p0,
                 const unsigned short* __restrict__ p1,
                 const unsigned short* __restrict__ p2,
                 const unsigned short* __restrict__ p3,
                 const float* __restrict__ res, float* __restrict__ out) {
  const int i = (blockIdx.x * 256 + threadIdx.x) * 4;
  const ushort4 a = *(const ushort4*)(p0 + i);
  const ushort4 b = *(const ushort4*)(p1 + i);
  const ushort4 c = *(const ushort4*)(p2 + i);
  const ushort4 d = *(const ushort4*)(p3 + i);
  float4 e = *(const float4*)(res + i);
  e.x += bf2f(a.x) + bf2f(b.x) + bf2f(c.x) + bf2f(d.x);
  e.y += bf2f(a.y) + bf2f(b.y) + bf2f(c.y) + bf2f(d.y);
  e.z += bf2f(a.z) + bf2f(b.z) + bf2f(c.z) + bf2f(d.z);
  e.w += bf2f(a.w) + bf2f(b.w) + bf2f(c.w) + bf2f(d.w);
  *(float4*)(out + i) = e;
}

// ---------------- LayerNorm (ln2, no mix) ----------------
template<bool MIX>
__global__ __launch_bounds__(256)
void ln_kernel(const float* __restrict__ x, const float* __restrict__ x0,
               const float* __restrict__ lam, const float* __restrict__ w,
               float* __restrict__ xm, unsigned short* __restrict__ xn) {
  __shared__ float red[8];
  const int row = blockIdx.x, t = threadIdx.x;
  const size_t base = (size_t)row << 10;
  float4 v = *(const float4*)(x + base + t * 4);
  if (MIX) {
    const float l0 = lam[0], l1 = lam[1];
    const float4 v0 = *(const float4*)(x0 + base + t * 4);
    v.x = l0 * v.x + l1 * v0.x;
    v.y = l0 * v.y + l1 * v0.y;
    v.z = l0 * v.z + l1 * v0.z;
    v.w = l0 * v.w + l1 * v0.w;
    *(float4*)(xm + base + t * 4) = v;
  }
  float s = v.x + v.y + v.z + v.w;
  float q = v.x * v.x + v.y * v.y + v.z * v.z + v.w * v.w;
#pragma unroll
  for (int off = 1; off < 64; off <<= 1) {
    s += __shfl_xor(s, off);
    q += __shfl_xor(q, off);
  }
  const int wid = t >> 6;
  if ((t & 63) == 0) { red[wid] = s; red[4 + wid] = q; }
  __syncthreads();
  s = red[0] + red[1] + red[2] + red[3];
  q = red[4] + red[5] + red[6] + red[7];
  const float mu = s * (1.0f / 1024.0f);
  const float var = q * (1.0f / 1024.0f) - mu * mu;
  const float rstd = rsqrtf(var + 1e-6f);
  const float4 wv = *(const float4*)(w + t * 4);
  ushort4 u;
  u.x = f2bf((v.x - mu) * rstd * wv.x);
  u.y = f2bf((v.y - mu) * rstd * wv.y);
  u.z = f2bf((v.z - mu) * rstd * wv.z);
  u.w = f2bf((v.w - mu) * rstd * wv.w);
  *(ushort4*)(xn + base + t * 4) = u;
}

// ---------------- GEMM (128-tile, 2-phase): used for wo ----------------
template<int EPI, int BM, int BK>
__global__ __launch_bounds__(256, 4)
void gemm_bt(const unsigned short* __restrict__ A,
             const unsigned short* __restrict__ Bt,
             void* __restrict__ Cout,
             const float* __restrict__ res,
             int M, int N, int K) {
  __shared__ unsigned short As[2][BM * BK];
  __shared__ unsigned short Bs[2][128 * BK];
  const int t = threadIdx.x;
  const int wid = t >> 6;
  const int lane = t & 63;
  const int ln = lane & 15, kg = lane >> 4;
  const int nbm = M / BM;
  const int xcd = (int)blockIdx.x & 7, rr = (int)blockIdx.x >> 3;
  const int slab = nbm >> 3;
  const int bm = xcd * slab + (rr % slab);
  const int bn = rr / slab;
  const int m0 = bm * BM, n0 = bn << 7;
  const int wrow = (BM == 128) ? ((wid >> 1) * 64) : 0;
  const int wcol = (BM == 128) ? ((wid & 1) * 64) : (wid * 32);
  constexpr int NJ = (BM == 128) ? 4 : 2;
  constexpr int LA = BM * BK / 2048;
  constexpr int LB = 128 * BK / 2048;
  constexpr int KC = BK / 32;

  f32x4 acc[4][NJ] = {};

  const unsigned short* Abase = A + (size_t)m0 * K;
  const unsigned short* Bbase = Bt + (size_t)n0 * K;

  auto swz = [&](int row, int chunk) -> int {
    if constexpr (BK == 32) return chunk ^ ((row >> 1) & 3);
    else                    return chunk ^ (row & 7);
  };

  auto STAGE = [&](int bb, int kt) {
#pragma unroll
    for (int p = 0; p < LA; p++) {
      const int e = t * 8 + p * 2048;
      const int r = e / BK;
      const int cs = swz(r, (e >> 3) & (BK / 8 - 1));
      GLOAD_LDS(Abase + (size_t)r * K + kt + cs * 8, &As[bb][p * 2048 + wid * 512]);
    }
#pragma unroll
    for (int p = 0; p < LB; p++) {
      const int e = t * 8 + p * 2048;
      const int r = e / BK;
      const int cs = swz(r, (e >> 3) & (BK / 8 - 1));
      GLOAD_LDS(Bbase + (size_t)r * K + kt + cs * 8, &Bs[bb][p * 2048 + wid * 512]);
    }
  };

  STAGE(0, 0);
  int cur = 0;
  const int nk = K / BK;
  for (int ki = 0; ki < nk; ki++) {
    if (ki + 1 < nk) {
      STAGE(cur ^ 1, (ki + 1) * BK);
      if constexpr (LA + LB == 4)
        asm volatile("s_waitcnt vmcnt(4)" ::: "memory");
      else
        asm volatile("s_waitcnt vmcnt(6)" ::: "memory");
    } else {
      asm volatile("s_waitcnt vmcnt(0)" ::: "memory");
    }
    __builtin_amdgcn_s_barrier();

#pragma unroll
    for (int c = 0; c < KC; c++) {
      bf16x8 af[4], bfr[NJ];
#pragma unroll
      for (int i = 0; i < 4; i++) {
        const int ra = wrow + i * 16 + ln;
        af[i] = *(const bf16x8*)(&As[cur][ra * BK + swz(ra, c * 4 + kg) * 8]);
      }
#pragma unroll
      for (int j = 0; j < NJ; j++) {
        const int rb = wcol + j * 16 + ln;
        bfr[j] = *(const bf16x8*)(&Bs[cur][rb * BK + swz(rb, c * 4 + kg) * 8]);
      }
#pragma unroll
      for (int i = 0; i < 4; i++)
#pragma unroll
        for (int j = 0; j < NJ; j++)
          acc[i][j] = __builtin_amdgcn_mfma_f32_16x16x32_bf16(af[i], bfr[j], acc[i][j], 0, 0, 0);
    }

    __builtin_amdgcn_s_barrier();
    cur ^= 1;
  }

#pragma unroll
  for (int i = 0; i < 4; i++) {
#pragma unroll
    for (int j = 0; j < NJ; j++) {
#pragma unroll
      for (int r = 0; r < 4; r++) {
        const int row = m0 + wrow + i * 16 + kg * 4 + r;
        const int col = n0 + wcol + j * 16 + ln;
        const size_t idx = (size_t)row * N + col;
        float v = acc[i][j][r];
        if (EPI == 0) {
          ((float*)Cout)[idx] = v;
        } else if (EPI == 1) {
          ((float*)Cout)[idx] = v + res[idx];
        } else if (EPI == 2) {
          v = fmaxf(v, 0.0f);
          ((unsigned short*)Cout)[idx] = f2bf(v * v);
        } else {
          ((unsigned short*)Cout)[idx] = f2bf(v);
        }
      }
    }
  }
}

// ---------------- GEMM 256x256 8-phase (T2+T3+T4+T5): qkv, fc, proj(K-split) ----
#define SWZ9(x) ((x) ^ ((((x) >> 9) & 1) << 5))

#define RD_A(BUF, QM)                                                          \
  {                                                                            \
    const char* sb_ = smem + (((BUF)*2 + 0) * 2 + (QM)) * 16384;               \
    _Pragma("unroll") for (int i_ = 0; i_ < 4; i_++)                           \
    _Pragma("unroll") for (int kc_ = 0; kc_ < 2; kc_++) {                      \
      int x_ = kc_ * 8192 + (wr * 64 + i_ * 16 + ln) * 64 + kg * 16;           \
      Af[i_][kc_] = *(const bf16x8*)(sb_ + SWZ9(x_));                          \
    }                                                                          \
  }

#define RD_B(BUF, QN, BARR)                                                    \
  {                                                                            \
    const char* sb_ = smem + (((BUF)*2 + 1) * 2 + (QN)) * 16384;               \
    _Pragma("unroll") for (int j_ = 0; j_ < 2; j_++)                           \
    _Pragma("unroll") for (int kc_ = 0; kc_ < 2; kc_++) {                      \
      int x_ = kc_ * 8192 + (wc * 32 + j_ * 16 + ln) * 64 + kg * 16;           \
      BARR[j_][kc_] = *(const bf16x8*)(sb_ + SWZ9(x_));                        \
    }                                                                          \
  }

#define MFMAQ(QM, QN, BARR)                                                    \
  _Pragma("unroll") for (int i_ = 0; i_ < 4; i_++)                             \
  _Pragma("unroll") for (int j_ = 0; j_ < 2; j_++)                             \
  _Pragma("unroll") for (int kc_ = 0; kc_ < 2; kc_++)                          \
    acc[QM][QN][i_][j_] = __builtin_amdgcn_mfma_f32_16x16x32_bf16(             \
        Af[i_][kc_], BARR[j_][kc_], acc[QM][QN][i_][j_], 0, 0, 0);

#define PHTAIL()                                                               \
  __builtin_amdgcn_s_barrier();                                                \
  asm volatile("s_waitcnt lgkmcnt(0)" ::: "memory");                           \
  __builtin_amdgcn_sched_barrier(0);                                           \
  __builtin_amdgcn_s_setprio(1)

#define PHEND()                                                                \
  __builtin_amdgcn_s_setprio(0);                                               \
  __builtin_amdgcn_s_barrier()

template<int EPI, bool KSPLIT4>
__global__ __launch_bounds__(512, 2)
void gemm256(const unsigned short* __restrict__ A,
             const unsigned short* __restrict__ Bt,
             void* __restrict__ Cout,
             int M, int N, int Kfull, int Klen, int nInner,
             unsigned short* __restrict__ o1, unsigned short* __restrict__ o2,
             unsigned short* __restrict__ o3) {
  extern __shared__ char smem[];
  const int tid = threadIdx.x;
  const int wid = tid >> 6, lane = tid & 63;
  const int wr = wid >> 2, wc = wid & 3;
  const int ln = lane & 15, kg = lane >> 4;
  int blkid = (int)blockIdx.x;
  int split = 0;
  if constexpr (KSPLIT4) {
    split = blkid / nInner;
    blkid -= split * nInner;
  }
  const int nbm = M >> 8;
  const int xcd = blkid & 7, rr = blkid >> 3;
  const int slab = nbm >> 3;
  const int bm = xcd * slab + (rr % slab);
  const int bn = rr / slab;
  const int m0 = bm << 8, n0 = bn << 8;
  const size_t K2 = (size_t)Kfull * 2;
  const size_t kb0 = (size_t)split * Klen * 2;
  const char* Ac = (const char*)A;
  const char* Bc = (const char*)Bt;

  f32x4 acc[2][2][4][2] = {};
  bf16x8 Af[4][2], B0[2][2], B1[2][2];

  auto STG = [&](int buf, int ab, int h, int tile) {
    const char* gb = ab ? Bc : Ac;
    const int ro = (ab ? n0 : m0) + h * 128;
    char* db = smem + ((buf * 2 + ab) * 2 + h) * 16384;
#pragma unroll
    for (int q = 0; q < 2; q++) {
      const int p0 = q * 8192 + tid * 16;
      const int lin = SWZ9(p0);
      GLOAD_LDS(gb + (size_t)(ro + ((lin >> 6) & 127)) * K2 + kb0 +
                    (size_t)tile * 128 + (lin >> 13) * 64 + (lin & 63),
                db + p0);
    }
  };

  STG(0, 0, 0, 0); STG(0, 0, 1, 0); STG(0, 1, 0, 0); STG(0, 1, 1, 0);
  STG(1, 0, 0, 1); STG(1, 1, 0, 1); STG(1, 1, 1, 1);
  asm volatile("s_waitcnt vmcnt(6)" ::: "memory");
  __builtin_amdgcn_s_barrier();

  const int niter = Klen >> 7;   // pairs of 64-wide K-tiles
  for (int it = 0; it < niter; it++) {
    const int tA = 2 * it, tB = tA + 1;
    const bool more = (it + 1 < niter);

    RD_A(0, 0); RD_B(0, 0, B0);
    STG(1, 0, 1, tB);
    PHTAIL(); MFMAQ(0, 0, B0); PHEND();
    RD_B(0, 1, B1);
    if (more) STG(0, 0, 0, tA + 2);
    PHTAIL(); MFMAQ(0, 1, B1); PHEND();
    RD_A(0, 1);
    if (more) STG(0, 1, 0, tA + 2);
    PHTAIL(); MFMAQ(1, 0, B0); PHEND();
    if (more) {
      STG(0, 1, 1, tA + 2);
      asm volatile("s_waitcnt vmcnt(6)" ::: "memory");
    } else {
      asm volatile("s_waitcnt vmcnt(0)" ::: "memory");
    }
    PHTAIL(); MFMAQ(1, 1, B1); PHEND();
    RD_A(1, 0); RD_B(1, 0, B0);
    if (more) STG(0, 0, 1, tA + 2);
    PHTAIL(); MFMAQ(0, 0, B0); PHEND();
    RD_B(1, 1, B1);
    if (more) STG(1, 0, 0, tB + 2);
    PHTAIL(); MFMAQ(0, 1, B1); PHEND();
    RD_A(1, 1);
    if (more) STG(1, 1, 0, tB + 2);
    PHTAIL(); MFMAQ(1, 0, B0); PHEND();
    if (more) {
      STG(1, 1, 1, tB + 2);
      asm volatile("s_waitcnt vmcnt(6)" ::: "memory");
    }
    PHTAIL(); MFMAQ(1, 1, B1); PHEND();
  }

  unsigned short* bout = (unsigned short*)Cout;
  if constexpr (KSPLIT4) {
    if (split == 1) bout = o1;
    else if (split == 2) bout = o2;
    else if (split == 3) bout = o3;
  }

#pragma unroll
  for (int qm = 0; qm < 2; qm++)
#pragma unroll
    for (int qn = 0; qn < 2; qn++)
#pragma unroll
      for (int i = 0; i < 4; i++)
#pragma unroll
        for (int j = 0; j < 2; j++)
#pragma unroll
          for (int r = 0; r < 4; r++) {
            const int row = m0 + qm * 128 + wr * 64 + i * 16 + kg * 4 + r;
            const int col = n0 + qn * 128 + wc * 32 + j * 16 + ln;
            const size_t idx = (size_t)row * N + col;
            float v = acc[qm][qn][i][j][r];
            if (EPI == 2) {
              v = fmaxf(v, 0.0f);
              ((unsigned short*)Cout)[idx] = f2bf(v * v);
            } else if (EPI == 3) {
              ((unsigned short*)Cout)[idx] = f2bf(v);
            } else {
              bout[idx] = f2bf(v);      // bf16 K-split partial
            }
          }
}

// ---------------- RoPE + RMSNorm + v-mix (qkv in bf16) ----------------
__global__ __launch_bounds__(256)
void rope_rms_kernel(const unsigned short* __restrict__ qkv,
                     const float* __restrict__ ct, const float* __restrict__ st,
                     const float* __restrict__ ve, const float* __restrict__ salam,
                     unsigned short* __restrict__ Qh, unsigned short* __restrict__ Kh,
                     unsigned short* __restrict__ Vt) {
  const int t = threadIdx.x;
  const int wid = t >> 6, i = t & 63;
  const int g = blockIdx.x * 4 + wid;      // (b,s,h)
  const int b = g >> 14;
  const int s = (g >> 3) & 2047;
  const int h = g & 7;
  const unsigned short* base = qkv + (size_t)(b * 2048 + s) * 3072 + h * 128;
  float c = 1.0f, sn = 0.0f;
  if (i < 32) { c = ct[s * 32 + i]; sn = st[s * 32 + i]; }
  const float q1 = bf2f(base[i]), q2 = bf2f(base[64 + i]);
  const float k1 = bf2f(base[1024 + i]), k2 = bf2f(base[1024 + 64 + i]);
  const float q1r = q1 * c + q2 * sn, q2r = q2 * c - q1 * sn;
  const float k1r = k1 * c + k2 * sn, k2r = k2 * c - k1 * sn;
  float sq = q1r * q1r + q2r * q2r;
  float sk = k1r * k1r + k2r * k2r;
#pragma unroll
  for (int off = 1; off < 64; off <<= 1) {
    sq += __shfl_xor(sq, off);
    sk += __shfl_xor(sk, off);
  }
  const float eps = 1.1920929e-7f;
  const float rq = rsqrtf(sq * (1.0f / 128.0f) + eps);
  const float rk = rsqrtf(sk * (1.0f / 128.0f) + eps);
  unsigned short* qp = Qh + (((size_t)(b * 2048 + s) * 8 + h) << 7);
  unsigned short* kp = Kh + (((size_t)(b * 2048 + s) * 8 + h) << 7);
  qp[i] = f2bf(q1r * rq); qp[64 + i] = f2bf(q2r * rq);
  kp[i] = f2bf(k1r * rk); kp[64 + i] = f2bf(k2r * rk);
  const float l0 = salam[0], l1 = salam[1];
  const float* vep = ve + (size_t)s * 1024 + h * 128;
  const float v1 = l0 * bf2f(base[2048 + i]) + l1 * vep[i];
  const float v2 = l0 * bf2f(base[2048 + 64 + i]) + l1 * vep[64 + i];
  unsigned short* vp = Vt + (((size_t)(b * 8 + h) * 128) << 11) + s;
  vp[(size_t)i << 11] = f2bf(v1);
  vp[(size_t)(64 + i) << 11] = f2bf(v2);
}

// ---------------- flash attention, doc-causal (fixed-shift softmax) ----------------
__global__ __launch_bounds__(512, 2)
void attn_kernel(const unsigned short* __restrict__ Qh,
                 const unsigned short* __restrict__ Kh,
                 const unsigned short* __restrict__ Vt,
                 const int* __restrict__ qstart,
                 unsigned short* __restrict__ Out) {
  extern __shared__ char asmem[];   // 128KB: K [4 kw][2 buf][8KB] @0; V same @65536

  const int blk = blockIdx.x;        // 256 blocks
  const int pid = blk >> 4;          // 0..15
  const int bh = blk & 15;
  const int b = bh >> 3, h = bh & 7;
  const int t = threadIdx.x;
  const int wid = t >> 6, lane = t & 63;
  const int qw = wid & 1, kw = wid >> 1;    // kw 0..3
  const int ln5 = lane & 31, hi = lane >> 5;
  const int tp = qw * 64 + lane;            // staging tid within kw-group
  const float SC = 0.12f * 1.4426950408889634f;
  const float MM = 23.0f;                   // fixed softmax shift (>= max |s*SC|)

  char* Kb = asmem + kw * 16384;
  char* Vb = asmem + 65536 + kw * 16384;

  const char* ksrc[4];
  const char* vsrc[4];
  char* kdst[4];
  char* vdst[4];
#pragma unroll
  for (int r = 0; r < 4; r++) {
    {
      const int e = tp * 16 + r * 2048;
      const int row = e >> 8;
      const int ch = (e >> 4) & 15;
      const int sch = ch ^ ((row ^ (row >> 3)) & 7);
      ksrc[r] = (const char*)(Kh + (((size_t)(b * 2048 + row) * 8 + h) << 7) + sch * 8);
      kdst[r] = Kb + r * 2048 + qw * 1024 + (lane << 4);
    }
    {
      const int e = tp * 16 + r * 2048;
      const int row = e >> 6;
      const int ch = (e >> 4) & 3;
      const int sch = ch ^ ((row >> 1) & 3);
      vsrc[r] = (const char*)(Vt + (((size_t)((b * 8 + h) * 128 + row)) << 11) + sch * 8);
      vdst[r] = Vb + r * 2048 + qw * 1024 + (lane << 4);
    }
  }

  auto STAGE = [&](int bb, int kt) {
    const size_t kof = (size_t)kt * 2048;
    const size_t vof = (size_t)kt * 2;
#pragma unroll
    for (int r = 0; r < 4; r++)
      GLOAD_LDS(ksrc[r] + kof, kdst[r] + bb * 8192);
#pragma unroll
    for (int r = 0; r < 4; r++)
      GLOAD_LDS(vsrc[r] + vof, vdst[r] + bb * 8192);
  };

  for (int ph = 0; ph < 2; ph++) {
    const int qt = ph ? (31 - pid) : pid;
    const int q0 = qt << 6;
    const int qrow = q0 + qw * 32;

    bf16x8 qf[8];
    {
      const unsigned short* qp =
          Qh + (((size_t)(b * 2048 + qrow + ln5) * 8 + h) << 7) + hi * 8;
#pragma unroll
      for (int c = 0; c < 8; c++) qf[c] = *(const bf16x8*)(qp + c * 16);
    }
    const int qid = qrow + ln5;
    const int qs = qstart[qid];
    int qsmax = qs;
#pragma unroll
    for (int off = 1; off < 32; off <<= 1)
      qsmax = max(qsmax, __shfl_xor(qsmax, off));

    float l = 0.0f;
    f32x16 o[4] = {};

    const int kt0 = qstart[q0] & ~31;
    const int T = (q0 + 64 - kt0) >> 5;

    __syncthreads();
    STAGE(0, kt0 + kw * 32);
    int cur = 0;
    const int nLoop = (T + 3) >> 2;

    for (int i = 0; i < nLoop; i++) {
      const int tid2 = 4 * i + kw;
      const bool hasnext = (tid2 + 4) < T;
      if (hasnext) {
        STAGE(cur ^ 1, kt0 + (tid2 + 4) * 32);
        asm volatile("s_waitcnt vmcnt(8)" ::: "memory");
      } else {
        asm volatile("s_waitcnt vmcnt(0)" ::: "memory");
      }
      __builtin_amdgcn_s_barrier();

      if (tid2 < T) {
        const int kt = kt0 + tid2 * 32;
        const unsigned short* ksb = (const unsigned short*)(Kb + cur * 8192);
        const unsigned short* vsb = (const unsigned short*)(Vb + cur * 8192);

        f32x16 sacc = {};
        {
          const int key = ln5;
          const int kx = (key ^ (key >> 3)) & 7;
          const unsigned short* krow = &ksb[key * 128];
          __builtin_amdgcn_s_setprio(1);
#pragma unroll
          for (int c = 0; c < 8; c++) {
            bf16x8 kf = *(const bf16x8*)(krow + (((2 * c + hi) ^ kx) << 3));
            sacc = __builtin_amdgcn_mfma_f32_32x32x16_bf16(kf, qf[c], sacc, 0, 0, 0);
          }
          __builtin_amdgcn_s_setprio(0);
        }

        const bool full = (kt + 32 <= qrow) && (kt >= qsmax);

        float p[16];
        if (full) {
#pragma unroll
          for (int i2 = 0; i2 < 16; i2++)
            p[i2] = exp2f(sacc[i2] * SC - MM);
        } else {
#pragma unroll
          for (int i2 = 0; i2 < 16; i2++) {
            const int key = kt + (i2 & 3) + 8 * (i2 >> 2) + 4 * hi;
            const bool valid = (key <= qid) && (key >= qs);
            const float ts = valid ? sacc[i2] * SC : -1e30f;
            p[i2] = exp2f(ts - MM);           // masked underflows to 0
          }
        }
        float t0 = p[0] + p[1], t1 = p[2] + p[3], t2 = p[4] + p[5], t3 = p[6] + p[7];
        float t4 = p[8] + p[9], t5 = p[10] + p[11], t6 = p[12] + p[13], t7 = p[14] + p[15];
        t0 += t1; t2 += t3; t4 += t5; t6 += t7;
        t0 += t2; t4 += t6;
        float sum = t0 + t4;
        sum += __shfl_xor(sum, 32);
        l += sum;

        bf16x8 pa[2];
#pragma unroll
        for (int bb2 = 0; bb2 < 2; bb2++) {
          unsigned int a0 = cvtpk(p[bb2 * 8 + 0], p[bb2 * 8 + 1]);
          unsigned int b0 = cvtpk(p[bb2 * 8 + 4], p[bb2 * 8 + 5]);
          unsigned int a1 = cvtpk(p[bb2 * 8 + 2], p[bb2 * 8 + 3]);
          unsigned int b1 = cvtpk(p[bb2 * 8 + 6], p[bb2 * 8 + 7]);
          plswap(a0, b0);
          plswap(a1, b1);
          U8 u; u.u[0] = a0; u.u[1] = a1; u.u[2] = b0; u.u[3] = b1;
          pa[bb2] = u.v;
        }

        __builtin_amdgcn_s_setprio(1);
#pragma unroll
        for (int dt = 0; dt < 4; dt++) {
          const int d = dt * 32 + ln5;
          const int dx = (d >> 1) & 3;
          const unsigned short* vrow = &vsb[d * 32];
#pragma unroll
          for (int ks = 0; ks < 2; ks++) {
            bf16x8 vf = *(const bf16x8*)(vrow + (((2 * ks + hi) ^ dx) << 3));
            o[dt] = __builtin_amdgcn_mfma_f32_32x32x16_bf16(pa[ks], vf, o[dt], 0, 0, 0);
          }
        }
        __builtin_amdgcn_s_setprio(0);
      }

      __builtin_amdgcn_s_barrier();
      cur ^= 1;
    }

    // ---- 4-way merge through (now idle) LDS: plain sums (shared fixed M) ----
    __syncthreads();
    float* oex = (float*)asmem;                 // [3][2 qw][64 lanes][65]
    float* llx = (float*)(asmem + 99840);       // [3][2][32]
    if (kw != 0) {
      if (lane < 32)
        llx[((kw - 1) * 2 + qw) * 32 + lane] = l;
      float* dst = oex + (((kw - 1) * 2 + qw) * 64 + lane) * 65;
#pragma unroll
      for (int dt = 0; dt < 4; dt++)
#pragma unroll
        for (int r = 0; r < 16; r++) dst[dt * 16 + r] = o[dt][r];
    }
    __syncthreads();
    if (kw == 0) {
      const float l1 = llx[(0 * 2 + qw) * 32 + ln5];
      const float l2 = llx[(1 * 2 + qw) * 32 + ln5];
      const float l3 = llx[(2 * 2 + qw) * 32 + ln5];
      const float inv = 1.0f / (l + l1 + l2 + l3);
      const float* s1 = oex + ((0 * 2 + qw) * 64 + lane) * 65;
      const float* s2 = oex + ((1 * 2 + qw) * 64 + lane) * 65;
      const float* s3 = oex + ((2 * 2 + qw) * 64 + lane) * 65;
#pragma unroll
      for (int r = 0; r < 16; r++) {
        const int crow = (r & 3) + 8 * (r >> 2) + 4 * hi;
        const float ivr = __shfl(inv, crow);
        const int q = qrow + crow;
        unsigned short* op = Out + (((size_t)(b * 2048 + q)) << 10) + h * 128 + ln5;
#pragma unroll
        for (int dt = 0; dt < 4; dt++)
          op[dt * 32] = f2bf((o[dt][r] + s1[dt * 16 + r] +
                              s2[dt * 16 + r] + s3[dt * 16 + r]) * ivr);
      }
    }
  }
}

// ---------------- launcher ----------------
extern "C" void kernel_launch(void* const* d_in, const int* in_sizes, int n_in,
                              void* d_out, int out_size, void* d_ws, size_t ws_size,
                              hipStream_t stream) {
  const float* x     = (const float*)d_in[0];
  const float* vemb  = (const float*)d_in[1];
  const float* x0    = (const float*)d_in[2];
  const float* lam   = (const float*)d_in[3];
  const float* slam  = (const float*)d_in[4];
  const float* ln1w  = (const float*)d_in[5];
  const float* ln2w  = (const float*)d_in[6];
  const float* wqkv  = (const float*)d_in[7];
  const float* wo    = (const float*)d_in[8];
  const float* wfc   = (const float*)d_in[9];
  const float* wproj = (const float*)d_in[10];
  const int*   ids   = (const int*)d_in[11];

  char* ws = (char*)d_ws;
  unsigned short* wqkvT  = (unsigned short*)(ws + 0);          //  6 MB
  unsigned short* woT    = (unsigned short*)(ws + 6291456);    //  2 MB
  unsigned short* wfcT   = (unsigned short*)(ws + 8388608);    //  8 MB
  unsigned short* wprojT = (unsigned short*)(ws + 16777216);   //  8 MB
  float*          xm     = (float*)(ws + 25165824);            // 16 MB
  unsigned short* qkv    = (unsigned short*)(ws + 41943040);   // 24 MB (bf16)
  unsigned short* hbuf   = (unsigned short*)(ws + 41943040);   // reuse (32 MB)
  unsigned short* xn1    = (unsigned short*)(ws + 92274688);   //  8 MB
  unsigned short* ao     = (unsigned short*)(ws + 92274688);   // reuse
  unsigned short* qh     = (unsigned short*)(ws + 100663296);  //  8 MB
  unsigned short* xn2    = (unsigned short*)(ws + 100663296);  // reuse
  unsigned short* kh     = (unsigned short*)(ws + 109051904);  //  8 MB
  unsigned short* vt     = (unsigned short*)(ws + 117440512);  //  8 MB
  float*          x2     = (float*)(ws + 109051904);           // reuse kh+vt (16 MB)
  float*          ctab   = (float*)(ws + 125829120);
  float*          stab   = (float*)(ws + 126091264);
  int*            qstart = (int*)(ws + 126353408);
  // bf16 K-split partials (8 MB each, all regions dead at proj time):
  unsigned short* P0 = (unsigned short*)(ws + 0);          // wqkvT+woT
  unsigned short* P1 = (unsigned short*)(ws + 8388608);    // wfcT (dead after fc)
  unsigned short* P2 = (unsigned short*)(ws + 25165824);   // xm lower half (dead after wo)
  unsigned short* P3 = (unsigned short*)(ws + 33554432);   // xm upper half

  static int attr_done = 0;
  if (!attr_done) {
    hipFuncSetAttribute((const void*)gemm256<3, false>,
                        hipFuncAttributeMaxDynamicSharedMemorySize, 131072);
    hipFuncSetAttribute((const void*)gemm256<2, false>,
                        hipFuncAttributeMaxDynamicSharedMemorySize, 131072);
    hipFuncSetAttribute((const void*)gemm256<4, true>,
                        hipFuncAttributeMaxDynamicSharedMemorySize, 131072);
    hipFuncSetAttribute((const void*)attn_kernel,
                        hipFuncAttributeMaxDynamicSharedMemorySize, 131072);
    attr_done = 1;
  }

  setup_kernel<<<dim3(16641), dim3(256), 0, stream>>>(
      wqkv, wo, wfc, wproj, wqkvT, woT, wfcT, wprojT,
      x, x0, lam, ln1w, xm, xn1, ctab, stab, ids, qstart);

  gemm256<3, false><<<dim3(192), dim3(512), 131072, stream>>>(
      xn1, wqkvT, (void*)qkv, 4096, 3072, 1024, 1024, 0, nullptr, nullptr, nullptr);
  rope_rms_kernel<<<dim3(8192), dim3(256), 0, stream>>>(qkv, ctab, stab, vemb, slam, qh, kh, vt);
  attn_kernel<<<dim3(256), dim3(512), 131072, stream>>>(qh, kh, vt, qstart, ao);
  gemm_bt<1, 64, 64><<<dim3(64 * 8), dim3(256), 0, stream>>>(ao, woT, (void*)x2, xm,
                                                             4096, 1024, 1024);
  ln_kernel<false><<<dim3(4096), dim3(256), 0, stream>>>(x2, (const float*)nullptr,
                                                         (const float*)nullptr, ln2w,
                                                         (float*)nullptr, xn2);
  gemm256<2, false><<<dim3(256), dim3(512), 131072, stream>>>(
      xn2, wfcT, (void*)hbuf, 4096, 4096, 1024, 1024, 0, nullptr, nullptr, nullptr);
  gemm256<4, true><<<dim3(256), dim3(512), 131072, stream>>>(
      hbuf, wprojT, (void*)P0, 4096, 1024, 4096, 1024, 64, P1, P2, P3);
  add5_kernel<<<dim3(4096), dim3(256), 0, stream>>>(P0, P1, P2, P3, x2, (float*)d_out);
}